// Round 1
// baseline (671.247 us; speedup 1.0000x reference)
//
#include <hip/hip_runtime.h>
#include <math.h>

#define N_TOK 4096
#define D_DIM 512
#define M_EXP 512
#define B_DIM 8
#define K_TOP 16
#define MB    4096          // M_EXP * B_DIM
#define UROW  4104          // (D_DIM+1) * B_DIM
#define EPSV  1e-8f

// ---------------- kernel: normalize x rows (one wave per row) ----------------
__global__ __launch_bounds__(256) void k_norm_x(const float* __restrict__ x,
                                                float* __restrict__ xn)
{
    int wave = threadIdx.x >> 6;
    int lane = threadIdx.x & 63;
    int n = blockIdx.x * 4 + wave;
    const float4* xp = (const float4*)&x[(size_t)n * D_DIM + lane * 8];
    float4 a = xp[0], b = xp[1];
    float s = a.x*a.x + a.y*a.y + a.z*a.z + a.w*a.w
            + b.x*b.x + b.y*b.y + b.z*b.z + b.w*b.w;
    #pragma unroll
    for (int off = 1; off < 64; off <<= 1) s += __shfl_xor(s, off);
    float inv = 1.0f / fmaxf(sqrtf(s), EPSV);
    float4* op = (float4*)&xn[(size_t)n * D_DIM + lane * 8];
    op[0] = make_float4(a.x*inv, a.y*inv, a.z*inv, a.w*inv);
    op[1] = make_float4(b.x*inv, b.y*inv, b.z*inv, b.w*inv);
}

// -------- kernel: normalize V columns (over D), emit Vn (D,M,B) + VnT (M,D,B) --------
__global__ __launch_bounds__(256) void k_norm_V(const float* __restrict__ V,
                                                float* __restrict__ Vn,
                                                float* __restrict__ VnT)
{
    int t = blockIdx.x * 256 + threadIdx.x;   // column id 0..4095 (m*8+b)
    float s = 0.f;
    for (int d = 0; d < D_DIM; ++d) { float v = V[(size_t)d * MB + t]; s += v * v; }
    float inv = 1.0f / fmaxf(sqrtf(s), EPSV);
    int m = t >> 3, b = t & 7;
    for (int d = 0; d < D_DIM; ++d) {
        float f = V[(size_t)d * MB + t] * inv;
        Vn[(size_t)d * MB + t] = f;
        VnT[(size_t)m * 4096 + d * 8 + b] = f;
    }
}

// -------- kernel: normalize U columns (over D+1 axis), keep layout (M, D+1, B) --------
__global__ __launch_bounds__(256) void k_norm_U(const float* __restrict__ U,
                                                float* __restrict__ Un)
{
    int t = blockIdx.x * 256 + threadIdx.x;   // 0..4095 (m*8+b)
    int m = t >> 3, b = t & 7;
    size_t base = (size_t)m * UROW + b;
    float s = 0.f;
    for (int p = 0; p <= D_DIM; ++p) { float u = U[base + p * 8]; s += u * u; }
    float inv = 1.0f / fmaxf(sqrtf(s), EPSV);
    for (int p = 0; p <= D_DIM; ++p) Un[base + p * 8] = U[base + p * 8] * inv;
}

// ---------------- kernel: h_all = xn (4096x512) @ Vn (512x4096), fp32 ----------------
__global__ __launch_bounds__(256) void k_gemm(const float* __restrict__ A,
                                              const float* __restrict__ Bm,
                                              float* __restrict__ C)
{
    __shared__ float As[16][64];   // As[k][row]
    __shared__ float Bs[16][64];   // Bs[k][col]
    int tid = threadIdx.x;
    int brow = blockIdx.y * 64;
    int bcol = blockIdx.x * 64;
    int tx = tid & 15, ty = tid >> 4;
    int a_r = tid >> 2, a_c = (tid & 3) * 4;
    int b_r = tid >> 4, b_c = (tid & 15) * 4;
    float acc[4][4] = {};
    for (int k0 = 0; k0 < D_DIM; k0 += 16) {
        float4 av = *(const float4*)&A[(size_t)(brow + a_r) * D_DIM + k0 + a_c];
        float4 bv = *(const float4*)&Bm[(size_t)(k0 + b_r) * MB + bcol + b_c];
        __syncthreads();
        As[a_c + 0][a_r] = av.x;
        As[a_c + 1][a_r] = av.y;
        As[a_c + 2][a_r] = av.z;
        As[a_c + 3][a_r] = av.w;
        *(float4*)&Bs[b_r][b_c] = bv;
        __syncthreads();
        #pragma unroll
        for (int kk = 0; kk < 16; ++kk) {
            float4 a4 = *(const float4*)&As[kk][ty * 4];
            float4 b4 = *(const float4*)&Bs[kk][tx * 4];
            float ar[4] = {a4.x, a4.y, a4.z, a4.w};
            float br[4] = {b4.x, b4.y, b4.z, b4.w};
            #pragma unroll
            for (int i = 0; i < 4; ++i)
                #pragma unroll
                for (int j = 0; j < 4; ++j)
                    acc[i][j] += ar[i] * br[j];
        }
    }
    #pragma unroll
    for (int i = 0; i < 4; ++i) {
        float4 v = make_float4(acc[i][0], acc[i][1], acc[i][2], acc[i][3]);
        *(float4*)&C[(size_t)(brow + ty * 4 + i) * MB + bcol + tx * 4] = v;
    }
}

// ---------------- kernel: energy[n,m] = sum_b h[n,m,b]^2 ----------------
__global__ __launch_bounds__(256) void k_energy(const float* __restrict__ h_all,
                                                float* __restrict__ energy)
{
    int g = blockIdx.x * 256 + threadIdx.x;   // 0..N*M-1
    const float4* hp = (const float4*)&h_all[(size_t)g * 8];
    float4 a = hp[0], b = hp[1];
    energy[g] = a.x*a.x + a.y*a.y + a.z*a.z + a.w*a.w
              + b.x*b.x + b.y*b.y + b.z*b.z + b.w*b.w;
}

// ---------------- kernel: top-16 per token (one wave per token) ----------------
__global__ __launch_bounds__(256) void k_topk(const float* __restrict__ energy,
                                              int* __restrict__ topk_idx,
                                              int* __restrict__ counts)
{
    int wave = threadIdx.x >> 6;
    int lane = threadIdx.x & 63;
    int n = blockIdx.x * 4 + wave;
    float ev[8];
    #pragma unroll
    for (int i = 0; i < 8; ++i) ev[i] = energy[(size_t)n * M_EXP + i * 64 + lane];
    for (int r = 0; r < K_TOP; ++r) {
        float bv = -1.0f; int bi = 0;
        #pragma unroll
        for (int i = 0; i < 8; ++i) {
            if (ev[i] > bv) { bv = ev[i]; bi = i * 64 + lane; }
        }
        #pragma unroll
        for (int off = 1; off < 64; off <<= 1) {
            float ov = __shfl_xor(bv, off);
            int   oi = __shfl_xor(bi, off);
            if (ov > bv || (ov == bv && oi < bi)) { bv = ov; bi = oi; }
        }
        if (lane == 0) {
            topk_idx[n * K_TOP + r] = bi;
            atomicAdd(&counts[bi], 1);
        }
        // mark winner as used (compile-time indices keep ev in registers)
        #pragma unroll
        for (int i = 0; i < 8; ++i)
            if (((bi >> 6) == i) && (lane == (bi & 63))) ev[i] = -INFINITY;
    }
}

// -------- kernel: per-token gather/compute: writes, x_hat, h_recon, x_out, aux parts --------
__global__ __launch_bounds__(256) void k_gather(const float* __restrict__ xn,
                                                const float* __restrict__ VnT,
                                                const float* __restrict__ Un,
                                                const float* __restrict__ h_all,
                                                const int* __restrict__ topk_idx,
                                                float* __restrict__ x_out,
                                                float* __restrict__ uncap,
                                                float* __restrict__ writer)
{
    int n = blockIdx.x;
    int t = threadIdx.x;
    __shared__ int   sh_idx[K_TOP];
    __shared__ float sh_h[K_TOP][B_DIM];
    __shared__ float sh_writes[D_DIM];
    __shared__ float red1[256];
    __shared__ float red2[256];
    __shared__ float s_inv;

    if (t < K_TOP) sh_idx[t] = topk_idx[n * K_TOP + t];
    __syncthreads();
    if (t < K_TOP * B_DIM) {
        int k = t >> 3, b = t & 7;
        sh_h[k][b] = h_all[(size_t)n * MB + sh_idx[k] * 8 + b];
    }
    __syncthreads();

    int d0 = t, d1 = t + 256;
    float w0 = 0.f, w1 = 0.f, xh0 = 0.f, xh1 = 0.f;
    for (int k = 0; k < K_TOP; ++k) {
        int m = sh_idx[k];
        const float4* u0p = (const float4*)&Un[(size_t)m * UROW + d0 * 8];
        const float4* u1p = (const float4*)&Un[(size_t)m * UROW + d1 * 8];
        const float4* v0p = (const float4*)&VnT[(size_t)m * 4096 + d0 * 8];
        const float4* v1p = (const float4*)&VnT[(size_t)m * 4096 + d1 * 8];
        float4 ua = u0p[0], ub = u0p[1];
        float4 uc = u1p[0], ud = u1p[1];
        float4 va = v0p[0], vb = v0p[1];
        float4 vc = v1p[0], vd = v1p[1];
        float4 ha = *(const float4*)&sh_h[k][0];
        float4 hb = *(const float4*)&sh_h[k][4];
        w0  += ua.x*ha.x + ua.y*ha.y + ua.z*ha.z + ua.w*ha.w
             + ub.x*hb.x + ub.y*hb.y + ub.z*hb.z + ub.w*hb.w;
        w1  += uc.x*ha.x + uc.y*ha.y + uc.z*ha.z + uc.w*ha.w
             + ud.x*hb.x + ud.y*hb.y + ud.z*hb.z + ud.w*hb.w;
        xh0 += va.x*ha.x + va.y*ha.y + va.z*ha.z + va.w*ha.w
             + vb.x*hb.x + vb.y*hb.y + vb.z*hb.z + vb.w*hb.w;
        xh1 += vc.x*ha.x + vc.y*ha.y + vc.z*ha.z + vc.w*ha.w
             + vd.x*hb.x + vd.y*hb.y + vd.z*hb.z + vd.w*hb.w;
    }
    sh_writes[d0] = w0;
    sh_writes[d1] = w1;

    float xv0 = xn[(size_t)n * D_DIM + d0];
    float xv1 = xn[(size_t)n * D_DIM + d1];
    float r0 = xv0 - xh0, r1 = xv1 - xh1;
    float y0 = xv0 + w0,  y1 = xv1 + w1;
    red1[t] = r0 * r0 + r1 * r1;
    red2[t] = y0 * y0 + y1 * y1;
    __syncthreads();
    for (int s = 128; s > 0; s >>= 1) {
        if (t < s) { red1[t] += red1[t + s]; red2[t] += red2[t + s]; }
        __syncthreads();
    }
    if (t == 0) {
        uncap[n] = red1[0];
        s_inv = 1.0f / fmaxf(sqrtf(red2[0]), EPSV);
    }
    __syncthreads();
    float inv = s_inv;
    x_out[(size_t)n * D_DIM + d0] = y0 * inv;
    x_out[(size_t)n * D_DIM + d1] = y1 * inv;

    // h_recon: 128 threads, one (k,b) each, full sum over d
    float sq = 0.f;
    if (t < K_TOP * B_DIM) {
        int k = t >> 3, b = t & 7;
        int m = sh_idx[k];
        const float* up = &Un[(size_t)m * UROW + b];
        float s = 0.f;
        #pragma unroll 8
        for (int d = 0; d < D_DIM; ++d) s += up[d * 8] * sh_writes[d];
        float diff = s - sh_h[k][b];
        sq = diff * diff;
    }
    red1[t] = sq;
    __syncthreads();
    for (int s = 128; s > 0; s >>= 1) {
        if (t < s) red1[t] += red1[t + s];
        __syncthreads();
    }
    if (t == 0) writer[n] = red1[0];
}

// ---------------- kernel: final scalar reductions + counts ----------------
__global__ __launch_bounds__(256) void k_finalize(const float* __restrict__ uncap,
                                                  const float* __restrict__ writer,
                                                  const int* __restrict__ counts,
                                                  float* __restrict__ out)
{
    __shared__ float ru[256], rw[256];
    int t = threadIdx.x;
    float su = 0.f, sw = 0.f;
    for (int i = t; i < N_TOK; i += 256) { su += uncap[i]; sw += writer[i]; }
    ru[t] = su; rw[t] = sw;
    __syncthreads();
    for (int s = 128; s > 0; s >>= 1) {
        if (t < s) { ru[t] += ru[t + s]; rw[t] += rw[t + s]; }
        __syncthreads();
    }
    if (t == 0)
        out[(size_t)N_TOK * D_DIM] = ru[0] / (float)N_TOK
                                   + rw[0] / (float)(N_TOK * K_TOP * B_DIM);
    for (int i = t; i < M_EXP; i += 256)
        out[(size_t)N_TOK * D_DIM + 1 + i] = (float)counts[i];
}

extern "C" void kernel_launch(void* const* d_in, const int* in_sizes, int n_in,
                              void* d_out, int out_size, void* d_ws, size_t ws_size,
                              hipStream_t stream)
{
    const float* x = (const float*)d_in[0];
    const float* V = (const float*)d_in[1];
    const float* U = (const float*)d_in[2];
    float* out = (float*)d_out;

    float* ws     = (float*)d_ws;
    float* xn     = ws;                        // 2,097,152 f
    float* Vn     = xn + 2097152;              // 2,097,152 f
    float* VnT    = Vn + 2097152;              // 2,097,152 f
    float* Un     = VnT + 2097152;             // 2,101,248 f
    float* h_all  = Un + 2101248;              // 16,777,216 f
    float* energy = h_all + 16777216;          // 2,097,152 f
    float* uncap  = energy + 2097152;          // 4096 f
    float* writer = uncap + 4096;              // 4096 f
    int*   topk_i = (int*)(writer + 4096);     // 65,536 i
    int*   counts = topk_i + 65536;            // 512 i
    // total ws use ~104.3 MB

    hipMemsetAsync(counts, 0, M_EXP * sizeof(int), stream);
    k_norm_x <<<N_TOK / 4, 256, 0, stream>>>(x, xn);
    k_norm_V <<<MB / 256, 256, 0, stream>>>(V, Vn, VnT);
    k_norm_U <<<MB / 256, 256, 0, stream>>>(U, Un);
    k_gemm   <<<dim3(MB / 64, N_TOK / 64), 256, 0, stream>>>(xn, Vn, h_all);
    k_energy <<<(N_TOK * M_EXP) / 256, 256, 0, stream>>>(h_all, energy);
    k_topk   <<<N_TOK / 4, 256, 0, stream>>>(energy, topk_i, counts);
    k_gather <<<N_TOK, 256, 0, stream>>>(xn, VnT, Un, h_all, topk_i, out, uncap, writer);
    k_finalize<<<1, 256, 0, stream>>>(uncap, writer, counts, out);
}

// Round 2
// 523.573 us; speedup vs baseline: 1.2821x; 1.2821x over previous
//
#include <hip/hip_runtime.h>
#include <hip/hip_bf16.h>
#include <math.h>

#define N_TOK 4096
#define D_DIM 512
#define M_EXP 512
#define B_DIM 8
#define K_TOP 16
#define MB    4096          // M_EXP * B_DIM
#define UROW  4104          // (D_DIM+1) * B_DIM
#define EPSV  1e-8f

typedef unsigned short ushort8 __attribute__((ext_vector_type(8)));

__device__ inline float b2f(unsigned short u) {
    union { unsigned int i; float f; } c;
    c.i = ((unsigned int)u) << 16;
    return c.f;
}

// ---------------- kernel: normalize x rows (one wave per row) ----------------
__global__ __launch_bounds__(256) void k_norm_x(const float* __restrict__ x,
                                                float* __restrict__ xn)
{
    int wave = threadIdx.x >> 6;
    int lane = threadIdx.x & 63;
    int n = blockIdx.x * 4 + wave;
    const float4* xp = (const float4*)&x[(size_t)n * D_DIM + lane * 8];
    float4 a = xp[0], b = xp[1];
    float s = a.x*a.x + a.y*a.y + a.z*a.z + a.w*a.w
            + b.x*b.x + b.y*b.y + b.z*b.z + b.w*b.w;
    #pragma unroll
    for (int off = 1; off < 64; off <<= 1) s += __shfl_xor(s, off);
    float inv = 1.0f / fmaxf(sqrtf(s), EPSV);
    float4* op = (float4*)&xn[(size_t)n * D_DIM + lane * 8];
    op[0] = make_float4(a.x*inv, a.y*inv, a.z*inv, a.w*inv);
    op[1] = make_float4(b.x*inv, b.y*inv, b.z*inv, b.w*inv);
}

// -------- normalize V columns (over D): Vn fp32 (D,M,B) for GEMM + bf16 slab --------
// UVb layout: expert m -> slab (m*2)*4096 = U[d*8+b] bf16, slab (m*2+1)*4096 = V[d*8+b]
__global__ __launch_bounds__(256) void k_norm_V(const float* __restrict__ V,
                                                float* __restrict__ Vn,
                                                __hip_bfloat16* __restrict__ UVb)
{
    int t = blockIdx.x * 256 + threadIdx.x;   // column id 0..4095 (m*8+b)
    float s = 0.f;
    for (int d = 0; d < D_DIM; ++d) { float v = V[(size_t)d * MB + t]; s += v * v; }
    float inv = 1.0f / fmaxf(sqrtf(s), EPSV);
    int m = t >> 3, b = t & 7;
    size_t vb = ((size_t)(m * 2 + 1)) << 12;
    for (int d = 0; d < D_DIM; ++d) {
        float f = V[(size_t)d * MB + t] * inv;
        Vn[(size_t)d * MB + t] = f;
        UVb[vb + d * 8 + b] = __float2bfloat16(f);
    }
}

// -------- normalize U columns (over D+1 axis), emit bf16 slab (pad row dropped) --------
__global__ __launch_bounds__(256) void k_norm_U(const float* __restrict__ U,
                                                __hip_bfloat16* __restrict__ UVb)
{
    int t = blockIdx.x * 256 + threadIdx.x;   // 0..4095 (m*8+b)
    int m = t >> 3, b = t & 7;
    size_t base = (size_t)m * UROW + b;
    float s = 0.f;
    for (int p = 0; p <= D_DIM; ++p) { float u = U[base + p * 8]; s += u * u; }
    float inv = 1.0f / fmaxf(sqrtf(s), EPSV);
    size_t ub = ((size_t)(m * 2)) << 12;
    for (int p = 0; p < D_DIM; ++p)
        UVb[ub + p * 8 + b] = __float2bfloat16(U[base + p * 8] * inv);
}

// ---------------- h_all = xn (4096x512) @ Vn (512x4096), fp32 ----------------
__global__ __launch_bounds__(256) void k_gemm(const float* __restrict__ A,
                                              const float* __restrict__ Bm,
                                              float* __restrict__ C)
{
    __shared__ float As[16][64];
    __shared__ float Bs[16][64];
    int tid = threadIdx.x;
    int brow = blockIdx.y * 64;
    int bcol = blockIdx.x * 64;
    int tx = tid & 15, ty = tid >> 4;
    int a_r = tid >> 2, a_c = (tid & 3) * 4;
    int b_r = tid >> 4, b_c = (tid & 15) * 4;
    float acc[4][4] = {};
    for (int k0 = 0; k0 < D_DIM; k0 += 16) {
        float4 av = *(const float4*)&A[(size_t)(brow + a_r) * D_DIM + k0 + a_c];
        float4 bv = *(const float4*)&Bm[(size_t)(k0 + b_r) * MB + bcol + b_c];
        __syncthreads();
        As[a_c + 0][a_r] = av.x;
        As[a_c + 1][a_r] = av.y;
        As[a_c + 2][a_r] = av.z;
        As[a_c + 3][a_r] = av.w;
        *(float4*)&Bs[b_r][b_c] = bv;
        __syncthreads();
        #pragma unroll
        for (int kk = 0; kk < 16; ++kk) {
            float4 a4 = *(const float4*)&As[kk][ty * 4];
            float4 b4 = *(const float4*)&Bs[kk][tx * 4];
            float ar[4] = {a4.x, a4.y, a4.z, a4.w};
            float br[4] = {b4.x, b4.y, b4.z, b4.w};
            #pragma unroll
            for (int i = 0; i < 4; ++i)
                #pragma unroll
                for (int j = 0; j < 4; ++j)
                    acc[i][j] += ar[i] * br[j];
        }
    }
    #pragma unroll
    for (int i = 0; i < 4; ++i) {
        float4 v = make_float4(acc[i][0], acc[i][1], acc[i][2], acc[i][3]);
        *(float4*)&C[(size_t)(brow + ty * 4 + i) * MB + bcol + tx * 4] = v;
    }
}

// ---------- top-16 per token (one wave per token), energy fused ----------
__global__ __launch_bounds__(256) void k_topk(const float* __restrict__ h_all,
                                              int* __restrict__ topk_idx,
                                              int* __restrict__ counts)
{
    int wave = threadIdx.x >> 6;
    int lane = threadIdx.x & 63;
    int n = blockIdx.x * 4 + wave;
    float ev[8];
    #pragma unroll
    for (int i = 0; i < 8; ++i) {
        int e = i * 64 + lane;
        const float4* hp = (const float4*)&h_all[(size_t)n * MB + e * 8];
        float4 a = hp[0], b = hp[1];
        ev[i] = a.x*a.x + a.y*a.y + a.z*a.z + a.w*a.w
              + b.x*b.x + b.y*b.y + b.z*b.z + b.w*b.w;
    }
    for (int r = 0; r < K_TOP; ++r) {
        float bv = -1.0f; int bi = 0;
        #pragma unroll
        for (int i = 0; i < 8; ++i) {
            if (ev[i] > bv) { bv = ev[i]; bi = i * 64 + lane; }
        }
        #pragma unroll
        for (int off = 1; off < 64; off <<= 1) {
            float ov = __shfl_xor(bv, off);
            int   oi = __shfl_xor(bi, off);
            if (ov > bv || (ov == bv && oi < bi)) { bv = ov; bi = oi; }
        }
        if (lane == 0) {
            topk_idx[n * K_TOP + r] = bi;
            atomicAdd(&counts[bi], 1);
        }
        #pragma unroll
        for (int i = 0; i < 8; ++i)
            if (((bi >> 6) == i) && (lane == (bi & 63))) ev[i] = -INFINITY;
    }
}

// -------- per-token gather/compute from bf16 UV slabs --------
__global__ __launch_bounds__(256) void k_gather(const float* __restrict__ xn,
                                                const __hip_bfloat16* __restrict__ UVbf,
                                                const float* __restrict__ h_all,
                                                const int* __restrict__ topk_idx,
                                                float* __restrict__ x_out,
                                                float* __restrict__ uncap,
                                                float* __restrict__ writer)
{
    const unsigned short* UV = (const unsigned short*)UVbf;
    int n = blockIdx.x;
    int t = threadIdx.x;
    __shared__ int   sh_idx[K_TOP];
    __shared__ float sh_h[K_TOP][B_DIM];
    __shared__ float sh_writes[D_DIM];
    __shared__ float red1[256];
    __shared__ float red2[256];
    __shared__ float s_inv;

    if (t < K_TOP) sh_idx[t] = topk_idx[n * K_TOP + t];
    __syncthreads();
    if (t < K_TOP * B_DIM) {
        int k = t >> 3, b = t & 7;
        sh_h[k][b] = h_all[(size_t)n * MB + sh_idx[k] * 8 + b];
    }
    __syncthreads();

    int midx[K_TOP];
    #pragma unroll
    for (int k = 0; k < K_TOP; ++k) midx[k] = sh_idx[k];

    int d0 = t, d1 = t + 256;
    float w0 = 0.f, w1 = 0.f, xh0 = 0.f, xh1 = 0.f;
    for (int k0 = 0; k0 < K_TOP; k0 += 4) {
        ushort8 ua[4], ub[4], va[4], vb[4];
        #pragma unroll
        for (int j = 0; j < 4; ++j) {
            size_t bu = ((size_t)(midx[k0 + j] * 2)) << 12;
            ua[j] = *(const ushort8*)&UV[bu + d0 * 8];
            ub[j] = *(const ushort8*)&UV[bu + d1 * 8];
            va[j] = *(const ushort8*)&UV[bu + 4096 + d0 * 8];
            vb[j] = *(const ushort8*)&UV[bu + 4096 + d1 * 8];
        }
        #pragma unroll
        for (int j = 0; j < 4; ++j) {
            const float* h = &sh_h[k0 + j][0];
            #pragma unroll
            for (int e = 0; e < 8; ++e) {
                float he = h[e];
                w0  += b2f(ua[j][e]) * he;
                w1  += b2f(ub[j][e]) * he;
                xh0 += b2f(va[j][e]) * he;
                xh1 += b2f(vb[j][e]) * he;
            }
        }
    }
    sh_writes[d0] = w0;
    sh_writes[d1] = w1;

    float xv0 = xn[(size_t)n * D_DIM + d0];
    float xv1 = xn[(size_t)n * D_DIM + d1];
    float r0 = xv0 - xh0, r1 = xv1 - xh1;
    float y0 = xv0 + w0,  y1 = xv1 + w1;
    red1[t] = r0 * r0 + r1 * r1;
    red2[t] = y0 * y0 + y1 * y1;
    __syncthreads();
    for (int s = 128; s > 0; s >>= 1) {
        if (t < s) { red1[t] += red1[t + s]; red2[t] += red2[t + s]; }
        __syncthreads();
    }
    if (t == 0) {
        uncap[n] = red1[0];
        s_inv = 1.0f / fmaxf(sqrtf(red2[0]), EPSV);
    }
    __syncthreads();
    float inv = s_inv;
    x_out[(size_t)n * D_DIM + d0] = y0 * inv;
    x_out[(size_t)n * D_DIM + d1] = y1 * inv;

    // h_recon: 256 threads, (k,b,half) each — half d-range, shfl-combine
    {
        int k = t >> 4, b = (t >> 1) & 7, half = t & 1;
        const unsigned short* up = UV + (((size_t)(sh_idx[k] * 2)) << 12) + b;
        float s = 0.f;
        int dbeg = half * 256;
        #pragma unroll 8
        for (int d = dbeg; d < dbeg + 256; ++d)
            s += b2f(up[d * 8]) * sh_writes[d];
        float so = __shfl_xor(s, 1);
        float full = s + so;
        float sq = 0.f;
        if (half == 0) {
            float diff = full - sh_h[k][b];
            sq = diff * diff;
        }
        __syncthreads();
        red1[t] = sq;
    }
    __syncthreads();
    for (int s = 128; s > 0; s >>= 1) {
        if (t < s) red1[t] += red1[t + s];
        __syncthreads();
    }
    if (t == 0) writer[n] = red1[0];
}

// ---------------- final scalar reductions + counts ----------------
__global__ __launch_bounds__(256) void k_finalize(const float* __restrict__ uncap,
                                                  const float* __restrict__ writer,
                                                  const int* __restrict__ counts,
                                                  float* __restrict__ out)
{
    __shared__ float ru[256], rw[256];
    int t = threadIdx.x;
    float su = 0.f, sw = 0.f;
    for (int i = t; i < N_TOK; i += 256) { su += uncap[i]; sw += writer[i]; }
    ru[t] = su; rw[t] = sw;
    __syncthreads();
    for (int s = 128; s > 0; s >>= 1) {
        if (t < s) { ru[t] += ru[t + s]; rw[t] += rw[t + s]; }
        __syncthreads();
    }
    if (t == 0)
        out[(size_t)N_TOK * D_DIM] = ru[0] / (float)N_TOK
                                   + rw[0] / (float)(N_TOK * K_TOP * B_DIM);
    for (int i = t; i < M_EXP; i += 256)
        out[(size_t)N_TOK * D_DIM + 1 + i] = (float)counts[i];
}

extern "C" void kernel_launch(void* const* d_in, const int* in_sizes, int n_in,
                              void* d_out, int out_size, void* d_ws, size_t ws_size,
                              hipStream_t stream)
{
    const float* x = (const float*)d_in[0];
    const float* V = (const float*)d_in[1];
    const float* U = (const float*)d_in[2];
    float* out = (float*)d_out;

    float* ws     = (float*)d_ws;
    float* xn     = ws;                        // 2,097,152 f
    float* Vn     = xn + 2097152;              // 2,097,152 f
    float* h_all  = Vn + 2097152;              // 16,777,216 f
    float* uncap  = h_all + 16777216;          // 4096 f
    float* writer = uncap + 4096;              // 4096 f
    int*   topk_i = (int*)(writer + 4096);     // 65,536 i
    int*   counts = topk_i + 65536;            // 512 i
    __hip_bfloat16* UVb = (__hip_bfloat16*)(counts + 512); // 2*512*4096 bf16 = 33.55 MB
    // total ws use ~117.7 MB

    hipMemsetAsync(counts, 0, M_EXP * sizeof(int), stream);
    k_norm_x <<<N_TOK / 4, 256, 0, stream>>>(x, xn);
    k_norm_V <<<MB / 256, 256, 0, stream>>>(V, Vn, UVb);
    k_norm_U <<<MB / 256, 256, 0, stream>>>(U, UVb);
    k_gemm   <<<dim3(MB / 64, N_TOK / 64), 256, 0, stream>>>(xn, Vn, h_all);
    k_topk   <<<N_TOK / 4, 256, 0, stream>>>(h_all, topk_i, counts);
    k_gather <<<N_TOK, 256, 0, stream>>>(xn, UVb, h_all, topk_i, out, uncap, writer);
    k_finalize<<<1, 256, 0, stream>>>(uncap, writer, counts, out);
}

// Round 3
// 410.021 us; speedup vs baseline: 1.6371x; 1.2769x over previous
//
#include <hip/hip_runtime.h>
#include <math.h>

#define N_TOK 4096
#define D_DIM 512
#define M_EXP 512
#define B_DIM 8
#define K_TOP 16
#define MB    4096          // M_EXP * B_DIM
#define UROW  4104          // (D_DIM+1) * B_DIM
#define EPSV  1e-8f
#define KTOT  1536          // 3 * D (split-bf16 K blocks)

typedef unsigned short ushort8 __attribute__((ext_vector_type(8)));
typedef short short8 __attribute__((ext_vector_type(8)));
typedef float f32x4 __attribute__((ext_vector_type(4)));

__device__ inline float b2f(unsigned short u) {
    union { unsigned int i; float f; } c;
    c.i = ((unsigned int)u) << 16;
    return c.f;
}
__device__ inline unsigned short f2b(float f) {     // RNE bf16
    union { float f; unsigned int i; } c; c.f = f;
    unsigned int lsb = (c.i >> 16) & 1;
    c.i += 0x7fffu + lsb;
    return (unsigned short)(c.i >> 16);
}
__device__ inline void gload_lds16(const unsigned short* g, unsigned short* l) {
    __builtin_amdgcn_global_load_lds(
        (const __attribute__((address_space(1))) unsigned int*)g,
        (__attribute__((address_space(3))) unsigned int*)l, 16, 0, 0);
}

// ------------- normalize x rows; emit xn fp32 + A' = [hi|hi|lo] bf16 -------------
__global__ __launch_bounds__(256) void k_norm_x(const float* __restrict__ x,
                                                float* __restrict__ xn,
                                                unsigned short* __restrict__ Abf)
{
    int wave = threadIdx.x >> 6;
    int lane = threadIdx.x & 63;
    int n = blockIdx.x * 4 + wave;
    const float4* xp = (const float4*)&x[(size_t)n * D_DIM + lane * 8];
    float4 a = xp[0], b = xp[1];
    float s = a.x*a.x + a.y*a.y + a.z*a.z + a.w*a.w
            + b.x*b.x + b.y*b.y + b.z*b.z + b.w*b.w;
    #pragma unroll
    for (int off = 1; off < 64; off <<= 1) s += __shfl_xor(s, off);
    float inv = 1.0f / fmaxf(sqrtf(s), EPSV);
    float v[8] = {a.x*inv, a.y*inv, a.z*inv, a.w*inv,
                  b.x*inv, b.y*inv, b.z*inv, b.w*inv};
    float4* op = (float4*)&xn[(size_t)n * D_DIM + lane * 8];
    op[0] = make_float4(v[0], v[1], v[2], v[3]);
    op[1] = make_float4(v[4], v[5], v[6], v[7]);
    ushort8 hi, lo;
    #pragma unroll
    for (int j = 0; j < 8; ++j) {
        unsigned short h = f2b(v[j]);
        hi[j] = h;
        lo[j] = f2b(v[j] - b2f(h));
    }
    size_t base = (size_t)n * KTOT + lane * 8;
    *(ushort8*)&Abf[base]        = hi;
    *(ushort8*)&Abf[base + 512]  = hi;
    *(ushort8*)&Abf[base + 1024] = lo;
}

// ------- normalize V cols; emit Bt' (col-major, [hi|lo|hi]) + UVb V slab -------
__global__ __launch_bounds__(256) void k_norm_V(const float* __restrict__ V,
                                                unsigned short* __restrict__ Btbf,
                                                unsigned short* __restrict__ UVb)
{
    int t = blockIdx.x * 256 + threadIdx.x;   // column id 0..4095 (m*8+b)
    float s = 0.f;
    for (int d = 0; d < D_DIM; ++d) { float v = V[(size_t)d * MB + t]; s += v * v; }
    float inv = 1.0f / fmaxf(sqrtf(s), EPSV);
    int m = t >> 3, b = t & 7;
    size_t vb = ((size_t)(m * 2 + 1)) << 12;
    size_t row = (size_t)t * KTOT;
    for (int d0 = 0; d0 < D_DIM; d0 += 8) {
        ushort8 hi, lo;
        #pragma unroll
        for (int j = 0; j < 8; ++j) {
            float f = V[(size_t)(d0 + j) * MB + t] * inv;
            unsigned short h = f2b(f);
            hi[j] = h;
            lo[j] = f2b(f - b2f(h));
            UVb[vb + (size_t)(d0 + j) * 8 + b] = h;
        }
        *(ushort8*)&Btbf[row + d0]        = hi;
        *(ushort8*)&Btbf[row + 512 + d0]  = lo;
        *(ushort8*)&Btbf[row + 1024 + d0] = hi;
    }
}

// -------- normalize U columns (over D+1 axis), emit bf16 slab (pad row dropped) --------
__global__ __launch_bounds__(256) void k_norm_U(const float* __restrict__ U,
                                                unsigned short* __restrict__ UVb)
{
    int t = blockIdx.x * 256 + threadIdx.x;   // 0..4095 (m*8+b)
    int m = t >> 3, b = t & 7;
    size_t base = (size_t)m * UROW + b;
    float s = 0.f;
    for (int p = 0; p <= D_DIM; ++p) { float u = U[base + p * 8]; s += u * u; }
    float inv = 1.0f / fmaxf(sqrtf(s), EPSV);
    size_t ub = ((size_t)(m * 2)) << 12;
    for (int p = 0; p < D_DIM; ++p)
        UVb[ub + p * 8 + b] = f2b(U[base + p * 8] * inv);
}

// ---- h_all = A'(4096x1536) @ B'(1536x4096) bf16 MFMA, m97-style 128x128 tile ----
__global__ __launch_bounds__(256) void k_gemm_bf16(const unsigned short* __restrict__ A,
                                                   const unsigned short* __restrict__ Bt,
                                                   float* __restrict__ C)
{
    __shared__ __align__(16) unsigned short As[128 * 64];  // [row][k]
    __shared__ __align__(16) unsigned short Bs[128 * 64];  // [col][k]

    int tid = threadIdx.x;
    int wid = tid >> 6;
    int lane = tid & 63;

    // XCD-aware swizzle (1024 % 8 == 0 -> simple form is bijective)
    int bid = blockIdx.x;
    int swz = (bid & 7) * 128 + (bid >> 3);
    int brow = (swz >> 5) * 128;
    int bcol = (swz & 31) * 128;

    int wr = wid >> 1, wc = wid & 1;

    // staging: issue q = wid*4+i covers rows [q*8, q*8+8), lane -> (row=l>>3, k=(l&7)*8)
    const unsigned short* aptr[4];
    const unsigned short* bptr[4];
    unsigned short* alds[4];
    unsigned short* blds[4];
    #pragma unroll
    for (int i = 0; i < 4; ++i) {
        int q = wid * 4 + i;
        int r = q * 8 + (lane >> 3);
        aptr[i] = A  + (size_t)(brow + r) * KTOT + (lane & 7) * 8;
        bptr[i] = Bt + (size_t)(bcol + r) * KTOT + (lane & 7) * 8;
        alds[i] = &As[q * 512];
        blds[i] = &Bs[q * 512];
    }

    int aofs0 = (wr * 64 + (lane & 15)) * 64 + (lane >> 4) * 8;
    int bofs0 = (wc * 64 + (lane & 15)) * 64 + (lane >> 4) * 8;

    f32x4 acc[4][4] = {};

    // prologue stage
    #pragma unroll
    for (int i = 0; i < 4; ++i) { gload_lds16(aptr[i], alds[i]); gload_lds16(bptr[i], blds[i]); }

    for (int t = 0; t < KTOT / 64; ++t) {
        __syncthreads();   // staging(t) complete (vmcnt drain) + prev compute done
        #pragma unroll
        for (int kc = 0; kc < 2; ++kc) {
            short8 af[4], bf_[4];
            #pragma unroll
            for (int m = 0; m < 4; ++m) af[m]  = *(const short8*)&As[aofs0 + m * 1024 + kc * 32];
            #pragma unroll
            for (int n = 0; n < 4; ++n) bf_[n] = *(const short8*)&Bs[bofs0 + n * 1024 + kc * 32];
            #pragma unroll
            for (int m = 0; m < 4; ++m)
                #pragma unroll
                for (int n = 0; n < 4; ++n)
                    acc[m][n] = __builtin_amdgcn_mfma_f32_16x16x32_bf16(
                        af[m], bf_[n], acc[m][n], 0, 0, 0);
        }
        __syncthreads();   // all waves done reading LDS
        if (t + 1 < KTOT / 64) {
            int k0 = (t + 1) * 64;
            #pragma unroll
            for (int i = 0; i < 4; ++i) {
                gload_lds16(aptr[i] + k0, alds[i]);
                gload_lds16(bptr[i] + k0, blds[i]);
            }
        }
    }

    // epilogue: C/D layout col=lane&15, row=(lane>>4)*4+reg  [verified m89/m91]
    #pragma unroll
    for (int m = 0; m < 4; ++m) {
        int row0 = brow + wr * 64 + m * 16 + (lane >> 4) * 4;
        #pragma unroll
        for (int n = 0; n < 4; ++n) {
            int col = bcol + wc * 64 + n * 16 + (lane & 15);
            #pragma unroll
            for (int r = 0; r < 4; ++r)
                C[(size_t)(row0 + r) * MB + col] = acc[m][n][r];
        }
    }
}

// ---------- top-16 per token (one wave per token), energy fused ----------
__global__ __launch_bounds__(256) void k_topk(const float* __restrict__ h_all,
                                              int* __restrict__ topk_idx,
                                              int* __restrict__ counts)
{
    int wave = threadIdx.x >> 6;
    int lane = threadIdx.x & 63;
    int n = blockIdx.x * 4 + wave;
    float ev[8];
    #pragma unroll
    for (int i = 0; i < 8; ++i) {
        int e = i * 64 + lane;
        const float4* hp = (const float4*)&h_all[(size_t)n * MB + e * 8];
        float4 a = hp[0], b = hp[1];
        ev[i] = a.x*a.x + a.y*a.y + a.z*a.z + a.w*a.w
              + b.x*b.x + b.y*b.y + b.z*b.z + b.w*b.w;
    }
    for (int r = 0; r < K_TOP; ++r) {
        float bv = -1.0f; int bi = 0;
        #pragma unroll
        for (int i = 0; i < 8; ++i) {
            if (ev[i] > bv) { bv = ev[i]; bi = i * 64 + lane; }
        }
        #pragma unroll
        for (int off = 1; off < 64; off <<= 1) {
            float ov = __shfl_xor(bv, off);
            int   oi = __shfl_xor(bi, off);
            if (ov > bv || (ov == bv && oi < bi)) { bv = ov; bi = oi; }
        }
        if (lane == 0) {
            topk_idx[n * K_TOP + r] = bi;
            atomicAdd(&counts[bi], 1);
        }
        #pragma unroll
        for (int i = 0; i < 8; ++i)
            if (((bi >> 6) == i) && (lane == (bi & 63))) ev[i] = -INFINITY;
    }
}

// -------- per-token gather/compute from bf16 UV slabs --------
__global__ __launch_bounds__(256) void k_gather(const float* __restrict__ xn,
                                                const unsigned short* __restrict__ UV,
                                                const float* __restrict__ h_all,
                                                const int* __restrict__ topk_idx,
                                                float* __restrict__ x_out,
                                                float* __restrict__ uncap,
                                                float* __restrict__ writer)
{
    int n = blockIdx.x;
    int t = threadIdx.x;
    __shared__ int   sh_idx[K_TOP];
    __shared__ float sh_h[K_TOP][B_DIM];
    __shared__ float sh_writes[D_DIM];
    __shared__ float red1[256];
    __shared__ float red2[256];
    __shared__ float s_inv;

    if (t < K_TOP) sh_idx[t] = topk_idx[n * K_TOP + t];
    __syncthreads();
    if (t < K_TOP * B_DIM) {
        int k = t >> 3, b = t & 7;
        sh_h[k][b] = h_all[(size_t)n * MB + sh_idx[k] * 8 + b];
    }
    __syncthreads();

    int midx[K_TOP];
    #pragma unroll
    for (int k = 0; k < K_TOP; ++k) midx[k] = sh_idx[k];

    int d0 = t, d1 = t + 256;
    float w0 = 0.f, w1 = 0.f, xh0 = 0.f, xh1 = 0.f;
    for (int k0 = 0; k0 < K_TOP; k0 += 4) {
        ushort8 ua[4], ub[4], va[4], vb[4];
        #pragma unroll
        for (int j = 0; j < 4; ++j) {
            size_t bu = ((size_t)(midx[k0 + j] * 2)) << 12;
            ua[j] = *(const ushort8*)&UV[bu + d0 * 8];
            ub[j] = *(const ushort8*)&UV[bu + d1 * 8];
            va[j] = *(const ushort8*)&UV[bu + 4096 + d0 * 8];
            vb[j] = *(const ushort8*)&UV[bu + 4096 + d1 * 8];
        }
        #pragma unroll
        for (int j = 0; j < 4; ++j) {
            const float* h = &sh_h[k0 + j][0];
            #pragma unroll
            for (int e = 0; e < 8; ++e) {
                float he = h[e];
                w0  += b2f(ua[j][e]) * he;
                w1  += b2f(ub[j][e]) * he;
                xh0 += b2f(va[j][e]) * he;
                xh1 += b2f(vb[j][e]) * he;
            }
        }
    }
    sh_writes[d0] = w0;
    sh_writes[d1] = w1;

    float xv0 = xn[(size_t)n * D_DIM + d0];
    float xv1 = xn[(size_t)n * D_DIM + d1];
    float r0 = xv0 - xh0, r1 = xv1 - xh1;
    float y0 = xv0 + w0,  y1 = xv1 + w1;
    red1[t] = r0 * r0 + r1 * r1;
    red2[t] = y0 * y0 + y1 * y1;
    __syncthreads();
    for (int s = 128; s > 0; s >>= 1) {
        if (t < s) { red1[t] += red1[t + s]; red2[t] += red2[t + s]; }
        __syncthreads();
    }
    if (t == 0) {
        uncap[n] = red1[0];
        s_inv = 1.0f / fmaxf(sqrtf(red2[0]), EPSV);
    }
    __syncthreads();
    float inv = s_inv;
    x_out[(size_t)n * D_DIM + d0] = y0 * inv;
    x_out[(size_t)n * D_DIM + d1] = y1 * inv;

    // h_recon: 256 threads, (k,b,half) each — half d-range, shfl-combine
    {
        int k = t >> 4, b = (t >> 1) & 7, half = t & 1;
        const unsigned short* up = UV + (((size_t)(sh_idx[k] * 2)) << 12) + b;
        float s = 0.f;
        int dbeg = half * 256;
        #pragma unroll 8
        for (int d = dbeg; d < dbeg + 256; ++d)
            s += b2f(up[d * 8]) * sh_writes[d];
        float so = __shfl_xor(s, 1);
        float full = s + so;
        float sq = 0.f;
        if (half == 0) {
            float diff = full - sh_h[k][b];
            sq = diff * diff;
        }
        __syncthreads();
        red1[t] = sq;
    }
    __syncthreads();
    for (int s = 128; s > 0; s >>= 1) {
        if (t < s) red1[t] += red1[t + s];
        __syncthreads();
    }
    if (t == 0) writer[n] = red1[0];
}

// ---------------- final scalar reductions + counts ----------------
__global__ __launch_bounds__(256) void k_finalize(const float* __restrict__ uncap,
                                                  const float* __restrict__ writer,
                                                  const int* __restrict__ counts,
                                                  float* __restrict__ out)
{
    __shared__ float ru[256], rw[256];
    int t = threadIdx.x;
    float su = 0.f, sw = 0.f;
    for (int i = t; i < N_TOK; i += 256) { su += uncap[i]; sw += writer[i]; }
    ru[t] = su; rw[t] = sw;
    __syncthreads();
    for (int s = 128; s > 0; s >>= 1) {
        if (t < s) { ru[t] += ru[t + s]; rw[t] += rw[t + s]; }
        __syncthreads();
    }
    if (t == 0)
        out[(size_t)N_TOK * D_DIM] = ru[0] / (float)N_TOK
                                   + rw[0] / (float)(N_TOK * K_TOP * B_DIM);
    for (int i = t; i < M_EXP; i += 256)
        out[(size_t)N_TOK * D_DIM + 1 + i] = (float)counts[i];
}

extern "C" void kernel_launch(void* const* d_in, const int* in_sizes, int n_in,
                              void* d_out, int out_size, void* d_ws, size_t ws_size,
                              hipStream_t stream)
{
    const float* x = (const float*)d_in[0];
    const float* V = (const float*)d_in[1];
    const float* U = (const float*)d_in[2];
    float* out = (float*)d_out;

    float* ws     = (float*)d_ws;
    float* xn     = ws;                        // 2,097,152 f
    float* h_all  = xn + 2097152;              // 16,777,216 f
    float* uncap  = h_all + 16777216;          // 4096 f
    float* writer = uncap + 4096;              // 4096 f
    int*   topk_i = (int*)(writer + 4096);     // 65,536 i
    int*   counts = topk_i + 65536;            // 512 i
    unsigned short* UVb  = (unsigned short*)(counts + 512); // 4,194,304 us (8.4 MB)
    unsigned short* Abf  = UVb + 4194304;      // 6,291,456 us (12.6 MB)
    unsigned short* Btbf = Abf + 6291456;      // 6,291,456 us (12.6 MB)
    // total ws use ~109.3 MB

    hipMemsetAsync(counts, 0, M_EXP * sizeof(int), stream);
    k_norm_x   <<<N_TOK / 4, 256, 0, stream>>>(x, xn, Abf);
    k_norm_V   <<<MB / 256, 256, 0, stream>>>(V, Btbf, UVb);
    k_norm_U   <<<MB / 256, 256, 0, stream>>>(U, UVb);
    k_gemm_bf16<<<1024, 256, 0, stream>>>(Abf, Btbf, h_all);
    k_topk     <<<N_TOK / 4, 256, 0, stream>>>(h_all, topk_i, counts);
    k_gather   <<<N_TOK, 256, 0, stream>>>(xn, UVb, h_all, topk_i, out, uncap, writer);
    k_finalize <<<1, 256, 0, stream>>>(uncap, writer, counts, out);
}

// Round 4
// 380.706 us; speedup vs baseline: 1.7632x; 1.0770x over previous
//
#include <hip/hip_runtime.h>
#include <math.h>

#define N_TOK 4096
#define D_DIM 512
#define M_EXP 512
#define B_DIM 8
#define K_TOP 16
#define MB    4096          // M_EXP * B_DIM
#define UROW  4104          // (D_DIM+1) * B_DIM
#define EPSV  1e-8f
#define KTOT  1536          // 3 * D (split-bf16 K blocks for GEMM1)

typedef unsigned short ushort8 __attribute__((ext_vector_type(8)));
typedef short short8 __attribute__((ext_vector_type(8)));
typedef float f32x4 __attribute__((ext_vector_type(4)));

__device__ inline float b2f(unsigned short u) {
    union { unsigned int i; float f; } c;
    c.i = ((unsigned int)u) << 16;
    return c.f;
}
__device__ inline unsigned short f2b(float f) {     // RNE bf16
    union { float f; unsigned int i; } c; c.f = f;
    unsigned int lsb = (c.i >> 16) & 1;
    c.i += 0x7fffu + lsb;
    return (unsigned short)(c.i >> 16);
}
__device__ inline void gload_lds16(const unsigned short* g, unsigned short* l) {
    __builtin_amdgcn_global_load_lds(
        (const __attribute__((address_space(1))) unsigned int*)g,
        (__attribute__((address_space(3))) unsigned int*)l, 16, 0, 0);
}

// ------------- normalize x rows; emit xn fp32 + A' = [hi|hi|lo] bf16 -------------
__global__ __launch_bounds__(256) void k_norm_x(const float* __restrict__ x,
                                                float* __restrict__ xn,
                                                unsigned short* __restrict__ Abf)
{
    int wave = threadIdx.x >> 6;
    int lane = threadIdx.x & 63;
    int n = blockIdx.x * 4 + wave;
    const float4* xp = (const float4*)&x[(size_t)n * D_DIM + lane * 8];
    float4 a = xp[0], b = xp[1];
    float s = a.x*a.x + a.y*a.y + a.z*a.z + a.w*a.w
            + b.x*b.x + b.y*b.y + b.z*b.z + b.w*b.w;
    #pragma unroll
    for (int off = 1; off < 64; off <<= 1) s += __shfl_xor(s, off);
    float inv = 1.0f / fmaxf(sqrtf(s), EPSV);
    float v[8] = {a.x*inv, a.y*inv, a.z*inv, a.w*inv,
                  b.x*inv, b.y*inv, b.z*inv, b.w*inv};
    float4* op = (float4*)&xn[(size_t)n * D_DIM + lane * 8];
    op[0] = make_float4(v[0], v[1], v[2], v[3]);
    op[1] = make_float4(v[4], v[5], v[6], v[7]);
    ushort8 hi, lo;
    #pragma unroll
    for (int j = 0; j < 8; ++j) {
        unsigned short h = f2b(v[j]);
        hi[j] = h;
        lo[j] = f2b(v[j] - b2f(h));
    }
    size_t base = (size_t)n * KTOT + lane * 8;
    *(ushort8*)&Abf[base]        = hi;
    *(ushort8*)&Abf[base + 512]  = hi;
    *(ushort8*)&Abf[base + 1024] = lo;
}

// ------- normalize V cols; emit Bt' (col-major [hi|lo|hi]) + WXt V-half -------
// WXt row (512+d), entry t=(m*8+b):  Vn[m][d][b]
__global__ __launch_bounds__(256) void k_norm_V(const float* __restrict__ V,
                                                unsigned short* __restrict__ Btbf,
                                                unsigned short* __restrict__ WXt)
{
    int t = blockIdx.x * 256 + threadIdx.x;   // column id 0..4095 (m*8+b)
    float s = 0.f;
    for (int d = 0; d < D_DIM; ++d) { float v = V[(size_t)d * MB + t]; s += v * v; }
    float inv = 1.0f / fmaxf(sqrtf(s), EPSV);
    size_t row = (size_t)t * KTOT;
    for (int d0 = 0; d0 < D_DIM; d0 += 8) {
        ushort8 hi, lo;
        #pragma unroll
        for (int j = 0; j < 8; ++j) {
            float f = V[(size_t)(d0 + j) * MB + t] * inv;
            unsigned short h = f2b(f);
            hi[j] = h;
            lo[j] = f2b(f - b2f(h));
            WXt[(size_t)(512 + d0 + j) * MB + t] = h;
        }
        *(ushort8*)&Btbf[row + d0]        = hi;
        *(ushort8*)&Btbf[row + 512 + d0]  = lo;
        *(ushort8*)&Btbf[row + 1024 + d0] = hi;
    }
}

// -- normalize U cols (over D+1); emit WXt U-half (row d, entry t) + U2t[t*512+d] --
__global__ __launch_bounds__(256) void k_norm_U(const float* __restrict__ U,
                                                unsigned short* __restrict__ WXt,
                                                unsigned short* __restrict__ U2t)
{
    int t = blockIdx.x * 256 + threadIdx.x;   // 0..4095 (m*8+b)
    int m = t >> 3, b = t & 7;
    size_t base = (size_t)m * UROW + b;
    float s = 0.f;
    for (int p = 0; p <= D_DIM; ++p) { float u = U[base + p * 8]; s += u * u; }
    float inv = 1.0f / fmaxf(sqrtf(s), EPSV);
    for (int p = 0; p < D_DIM; ++p) {
        unsigned short h = f2b(U[base + p * 8] * inv);
        WXt[(size_t)p * MB + t] = h;
        U2t[(size_t)t * D_DIM + p] = h;
    }
}

// ---------------- generic m97-style bf16 GEMM ----------------
// A row-major (rows x KDIM), Bt col-major (Bt[col*KDIM + k]), output 4096 x (NCB*NT)
// OUTMODE 0: C fp32.  1: C fp32 + bf16 Cb for col<512 (ld 512).  2: Cb bf16 only.
template<int MT, int NT, int KDIM, int LDC, int NCB, int OUTMODE>
__global__ __launch_bounds__(256) void k_gemm_t(const unsigned short* __restrict__ A,
                                                const unsigned short* __restrict__ Bt,
                                                float* __restrict__ C,
                                                unsigned short* __restrict__ Cb)
{
    __shared__ __align__(16) unsigned short As[MT * 64];
    __shared__ __align__(16) unsigned short Bs[NT * 64];

    constexpr int NWG  = (4096 / MT) * NCB;
    constexpr int AISS = MT / 32;
    constexpr int BISS = NT / 32;
    constexpr int MR   = MT / 32;     // per-wave m repeats (wave tile MT/2)
    constexpr int NR   = NT / 32;

    int tid = threadIdx.x;
    int wid = tid >> 6;
    int lane = tid & 63;

    int bid = blockIdx.x;
    int swz = (bid & 7) * (NWG >> 3) + (bid >> 3);
    int brow = (swz / NCB) * MT;
    int bcol = (swz % NCB) * NT;
    int wr = wid >> 1, wc = wid & 1;

    const unsigned short* aptr[AISS];
    const unsigned short* bptr[BISS];
    unsigned short* alds[AISS];
    unsigned short* blds[BISS];
    #pragma unroll
    for (int i = 0; i < AISS; ++i) {
        int q = wid * AISS + i;
        int r = q * 8 + (lane >> 3);
        aptr[i] = A + (size_t)(brow + r) * KDIM + (lane & 7) * 8;
        alds[i] = &As[q * 512];
    }
    #pragma unroll
    for (int i = 0; i < BISS; ++i) {
        int q = wid * BISS + i;
        int r = q * 8 + (lane >> 3);
        bptr[i] = Bt + (size_t)(bcol + r) * KDIM + (lane & 7) * 8;
        blds[i] = &Bs[q * 512];
    }

    int aofs0 = (wr * (MT / 2) + (lane & 15)) * 64 + (lane >> 4) * 8;
    int bofs0 = (wc * (NT / 2) + (lane & 15)) * 64 + (lane >> 4) * 8;

    f32x4 acc[MR][NR] = {};

    #pragma unroll
    for (int i = 0; i < AISS; ++i) gload_lds16(aptr[i], alds[i]);
    #pragma unroll
    for (int i = 0; i < BISS; ++i) gload_lds16(bptr[i], blds[i]);

    for (int t = 0; t < KDIM / 64; ++t) {
        __syncthreads();
        #pragma unroll
        for (int kc = 0; kc < 2; ++kc) {
            short8 af[MR], bf_[NR];
            #pragma unroll
            for (int m = 0; m < MR; ++m) af[m]  = *(const short8*)&As[aofs0 + m * 1024 + kc * 32];
            #pragma unroll
            for (int n = 0; n < NR; ++n) bf_[n] = *(const short8*)&Bs[bofs0 + n * 1024 + kc * 32];
            #pragma unroll
            for (int m = 0; m < MR; ++m)
                #pragma unroll
                for (int n = 0; n < NR; ++n)
                    acc[m][n] = __builtin_amdgcn_mfma_f32_16x16x32_bf16(
                        af[m], bf_[n], acc[m][n], 0, 0, 0);
        }
        __syncthreads();
        if (t + 1 < KDIM / 64) {
            int k0 = (t + 1) * 64;
            #pragma unroll
            for (int i = 0; i < AISS; ++i) gload_lds16(aptr[i] + k0, alds[i]);
            #pragma unroll
            for (int i = 0; i < BISS; ++i) gload_lds16(bptr[i] + k0, blds[i]);
        }
    }

    // C/D layout: col=lane&15, row=(lane>>4)*4+reg  [verified m89/m91]
    #pragma unroll
    for (int m = 0; m < MR; ++m) {
        int row0 = brow + wr * (MT / 2) + m * 16 + (lane >> 4) * 4;
        #pragma unroll
        for (int n = 0; n < NR; ++n) {
            int col = bcol + wc * (NT / 2) + n * 16 + (lane & 15);
            #pragma unroll
            for (int r = 0; r < 4; ++r) {
                float v = acc[m][n][r];
                int row = row0 + r;
                if (OUTMODE == 0) {
                    C[(size_t)row * LDC + col] = v;
                } else if (OUTMODE == 1) {
                    C[(size_t)row * LDC + col] = v;
                    if (col < 512) Cb[(size_t)row * 512 + col] = f2b(v);
                } else {
                    Cb[(size_t)row * LDC + col] = f2b(v);
                }
            }
        }
    }
}

// ---------- top-16 per token (one wave per token) + masked bf16 h emission ----------
__global__ __launch_bounds__(256) void k_topk(const float* __restrict__ h_all,
                                              int* __restrict__ topk_idx,
                                              int* __restrict__ counts,
                                              unsigned short* __restrict__ hb)
{
    int wave = threadIdx.x >> 6;
    int lane = threadIdx.x & 63;
    int n = blockIdx.x * 4 + wave;
    float ev[8];
    #pragma unroll
    for (int i = 0; i < 8; ++i) {
        int e = i * 64 + lane;
        const float4* hp = (const float4*)&h_all[(size_t)n * MB + e * 8];
        float4 a = hp[0], b = hp[1];
        ev[i] = a.x*a.x + a.y*a.y + a.z*a.z + a.w*a.w
              + b.x*b.x + b.y*b.y + b.z*b.z + b.w*b.w;
    }
    for (int r = 0; r < K_TOP; ++r) {
        float bv = -1.0f; int bi = 0;
        #pragma unroll
        for (int i = 0; i < 8; ++i) {
            if (ev[i] > bv) { bv = ev[i]; bi = i * 64 + lane; }
        }
        #pragma unroll
        for (int off = 1; off < 64; off <<= 1) {
            float ov = __shfl_xor(bv, off);
            int   oi = __shfl_xor(bi, off);
            if (ov > bv || (ov == bv && oi < bi)) { bv = ov; bi = oi; }
        }
        if (lane == 0) {
            topk_idx[n * K_TOP + r] = bi;
            atomicAdd(&counts[bi], 1);
        }
        #pragma unroll
        for (int i = 0; i < 8; ++i)
            if (((bi >> 6) == i) && (lane == (bi & 63))) ev[i] = -INFINITY;
    }
    // emit masked bf16 h row: selected experts keep h, others 0
    #pragma unroll
    for (int i = 0; i < 8; ++i) {
        int e = i * 64 + lane;
        const float4* hp = (const float4*)&h_all[(size_t)n * MB + e * 8];
        float4 a = hp[0], b = hp[1];
        bool sel = (ev[i] == -INFINITY);
        ushort8 o;
        o[0] = sel ? f2b(a.x) : 0;  o[1] = sel ? f2b(a.y) : 0;
        o[2] = sel ? f2b(a.z) : 0;  o[3] = sel ? f2b(a.w) : 0;
        o[4] = sel ? f2b(b.x) : 0;  o[5] = sel ? f2b(b.y) : 0;
        o[6] = sel ? f2b(b.z) : 0;  o[7] = sel ? f2b(b.w) : 0;
        *(ushort8*)&hb[(size_t)n * MB + e * 8] = o;
    }
}

// ---------- token-major finalize: x_out, uncap, writer (one wave per token) ----------
__global__ __launch_bounds__(256) void k_fin_tok(const float* __restrict__ xn,
                                                 const float* __restrict__ wx,
                                                 const unsigned short* __restrict__ hrecon,
                                                 const float* __restrict__ h_all,
                                                 const int* __restrict__ topk_idx,
                                                 float* __restrict__ x_out,
                                                 float* __restrict__ uncap,
                                                 float* __restrict__ writer)
{
    int wave = threadIdx.x >> 6;
    int lane = threadIdx.x & 63;
    int n = blockIdx.x * 4 + wave;

    const float4* xp = (const float4*)&xn[(size_t)n * D_DIM + lane * 8];
    const float4* wp = (const float4*)&wx[(size_t)n * 1024 + lane * 8];
    const float4* ap = (const float4*)&wx[(size_t)n * 1024 + 512 + lane * 8];
    float4 x0 = xp[0], x1 = xp[1];
    float4 w0 = wp[0], w1 = wp[1];
    float4 a0 = ap[0], a1 = ap[1];
    float y[8] = {x0.x+w0.x, x0.y+w0.y, x0.z+w0.z, x0.w+w0.w,
                  x1.x+w1.x, x1.y+w1.y, x1.z+w1.z, x1.w+w1.w};
    float r[8] = {x0.x-a0.x, x0.y-a0.y, x0.z-a0.z, x0.w-a0.w,
                  x1.x-a1.x, x1.y-a1.y, x1.z-a1.z, x1.w-a1.w};
    float s1 = 0.f, s2 = 0.f;
    #pragma unroll
    for (int j = 0; j < 8; ++j) { s1 += r[j]*r[j]; s2 += y[j]*y[j]; }
    #pragma unroll
    for (int off = 1; off < 64; off <<= 1) {
        s1 += __shfl_xor(s1, off);
        s2 += __shfl_xor(s2, off);
    }
    float inv = 1.0f / fmaxf(sqrtf(s2), EPSV);
    float4* op = (float4*)&x_out[(size_t)n * D_DIM + lane * 8];
    op[0] = make_float4(y[0]*inv, y[1]*inv, y[2]*inv, y[3]*inv);
    op[1] = make_float4(y[4]*inv, y[5]*inv, y[6]*inv, y[7]*inv);

    // writer part: 128 (k,b) pairs, 2 per lane
    float acc = 0.f;
    #pragma unroll
    for (int pp = 0; pp < 2; ++pp) {
        int p = lane + pp * 64;
        int m = topk_idx[n * K_TOP + (p >> 3)];
        size_t id = (size_t)n * MB + m * 8 + (p & 7);
        float d = b2f(hrecon[id]) - h_all[id];
        acc += d * d;
    }
    #pragma unroll
    for (int off = 1; off < 64; off <<= 1) acc += __shfl_xor(acc, off);
    if (lane == 0) { uncap[n] = s1; writer[n] = acc; }
}

// ---------------- final scalar reductions + counts ----------------
__global__ __launch_bounds__(256) void k_finalize(const float* __restrict__ uncap,
                                                  const float* __restrict__ writer,
                                                  const int* __restrict__ counts,
                                                  float* __restrict__ out)
{
    __shared__ float ru[256], rw[256];
    int t = threadIdx.x;
    float su = 0.f, sw = 0.f;
    for (int i = t; i < N_TOK; i += 256) { su += uncap[i]; sw += writer[i]; }
    ru[t] = su; rw[t] = sw;
    __syncthreads();
    for (int s = 128; s > 0; s >>= 1) {
        if (t < s) { ru[t] += ru[t + s]; rw[t] += rw[t + s]; }
        __syncthreads();
    }
    if (t == 0)
        out[(size_t)N_TOK * D_DIM] = ru[0] / (float)N_TOK
                                   + rw[0] / (float)(N_TOK * K_TOP * B_DIM);
    for (int i = t; i < M_EXP; i += 256)
        out[(size_t)N_TOK * D_DIM + 1 + i] = (float)counts[i];
}

extern "C" void kernel_launch(void* const* d_in, const int* in_sizes, int n_in,
                              void* d_out, int out_size, void* d_ws, size_t ws_size,
                              hipStream_t stream)
{
    const float* x = (const float*)d_in[0];
    const float* V = (const float*)d_in[1];
    const float* U = (const float*)d_in[2];
    float* out = (float*)d_out;

    float* ws     = (float*)d_ws;
    float* xn     = ws;                        // 2,097,152 f   (8.4 MB)
    float* h_all  = xn + 2097152;              // 16,777,216 f  (67.1 MB)
    float* wx     = h_all + 16777216;          // 4,194,304 f   (16.8 MB) writes|xhat
    float* uncap  = wx + 4194304;              // 4096 f
    float* writer = uncap + 4096;              // 4096 f
    int*   topk_i = (int*)(writer + 4096);     // 65,536 i
    int*   counts = topk_i + 65536;            // 512 i  (+pad 512)
    unsigned short* U2t     = (unsigned short*)(counts + 1024);  // 2,097,152 us (4.2 MB)
    unsigned short* WXt     = U2t + 2097152;   // 4,194,304 us (8.4 MB)
    unsigned short* writesb = WXt + 4194304;   // 2,097,152 us (4.2 MB)
    unsigned short* R       = writesb + 2097152; // 16,777,216 us (33.6 MB) shared region
    unsigned short* Abf     = R;               // 6,291,456 us  (gemm1 A')
    unsigned short* Btbf    = R + 6291456;     // 6,291,456 us  (gemm1 B')
    unsigned short* hb      = R;               // 16,777,216 us (after gemm1)
    unsigned short* hrecon  = R;               // 16,777,216 us (after gemm23)
    // total ws use ~143 MB

    hipMemsetAsync(counts, 0, M_EXP * sizeof(int), stream);
    k_norm_x <<<N_TOK / 4, 256, 0, stream>>>(x, xn, Abf);
    k_norm_V <<<MB / 256, 256, 0, stream>>>(V, Btbf, WXt);
    k_norm_U <<<MB / 256, 256, 0, stream>>>(U, WXt, U2t);
    // GEMM1: h_all = A'(4096x1536) @ B'(1536x4096), split-bf16, fp32 out
    k_gemm_t<128, 128, KTOT, 4096, 32, 0><<<1024, 256, 0, stream>>>(Abf, Btbf, h_all, nullptr);
    k_topk   <<<N_TOK / 4, 256, 0, stream>>>(h_all, topk_i, counts, hb);
    // GEMM23: wx = hb(4096x4096) @ WXt^T -> (4096x1024) [writes|xhat], + writesb bf16
    k_gemm_t<128, 64, 4096, 1024, 16, 1><<<512, 256, 0, stream>>>(hb, WXt, wx, writesb);
    // GEMM4: hrecon = writesb(4096x512) @ U2t^T -> (4096x4096) bf16
    k_gemm_t<128, 128, 512, 4096, 32, 2><<<1024, 256, 0, stream>>>(writesb, U2t, nullptr, hrecon);
    k_fin_tok<<<N_TOK / 4, 256, 0, stream>>>(xn, wx, hrecon, h_all, topk_i, out, uncap, writer);
    k_finalize<<<1, 256, 0, stream>>>(uncap, writer, counts, out);
}

// Round 5
// 282.523 us; speedup vs baseline: 2.3759x; 1.3475x over previous
//
#include <hip/hip_runtime.h>
#include <math.h>

#define N_TOK 4096
#define D_DIM 512
#define M_EXP 512
#define B_DIM 8
#define K_TOP 16
#define MB    4096          // M_EXP * B_DIM
#define UROW  4104          // (D_DIM+1) * B_DIM
#define EPSV  1e-8f
#define KTOT  1536          // 3 * D (split-bf16 K blocks for GEMM1)

typedef unsigned short ushort8 __attribute__((ext_vector_type(8)));
typedef short short8 __attribute__((ext_vector_type(8)));
typedef float f32x4 __attribute__((ext_vector_type(4)));

__device__ inline float b2f(unsigned short u) {
    union { unsigned int i; float f; } c;
    c.i = ((unsigned int)u) << 16;
    return c.f;
}
__device__ inline unsigned short f2b(float f) {     // RNE bf16
    union { float f; unsigned int i; } c; c.f = f;
    unsigned int lsb = (c.i >> 16) & 1;
    c.i += 0x7fffu + lsb;
    return (unsigned short)(c.i >> 16);
}
__device__ inline void gload_lds16(const unsigned short* g, unsigned short* l) {
    __builtin_amdgcn_global_load_lds(
        (const __attribute__((address_space(1))) unsigned int*)g,
        (__attribute__((address_space(3))) unsigned int*)l, 16, 0, 0);
}

// ------------- normalize x rows; emit xn fp32 + A' = [hi|hi|lo] bf16 -------------
__global__ __launch_bounds__(256) void k_norm_x(const float* __restrict__ x,
                                                float* __restrict__ xn,
                                                unsigned short* __restrict__ Abf)
{
    int wave = threadIdx.x >> 6;
    int lane = threadIdx.x & 63;
    int n = blockIdx.x * 4 + wave;
    const float4* xp = (const float4*)&x[(size_t)n * D_DIM + lane * 8];
    float4 a = xp[0], b = xp[1];
    float s = a.x*a.x + a.y*a.y + a.z*a.z + a.w*a.w
            + b.x*b.x + b.y*b.y + b.z*b.z + b.w*b.w;
    #pragma unroll
    for (int off = 1; off < 64; off <<= 1) s += __shfl_xor(s, off);
    float inv = 1.0f / fmaxf(sqrtf(s), EPSV);
    float v[8] = {a.x*inv, a.y*inv, a.z*inv, a.w*inv,
                  b.x*inv, b.y*inv, b.z*inv, b.w*inv};
    float4* op = (float4*)&xn[(size_t)n * D_DIM + lane * 8];
    op[0] = make_float4(v[0], v[1], v[2], v[3]);
    op[1] = make_float4(v[4], v[5], v[6], v[7]);
    ushort8 hi, lo;
    #pragma unroll
    for (int j = 0; j < 8; ++j) {
        unsigned short h = f2b(v[j]);
        hi[j] = h;
        lo[j] = f2b(v[j] - b2f(h));
    }
    size_t base = (size_t)n * KTOT + lane * 8;
    *(ushort8*)&Abf[base]        = hi;
    *(ushort8*)&Abf[base + 512]  = hi;
    *(ushort8*)&Abf[base + 1024] = lo;
}

// ---- V column-norm partials: part[s][t] = sum_{d in slab s (32 rows)} V[d][t]^2 ----
__global__ __launch_bounds__(256) void k_vnorm_part(const float* __restrict__ V,
                                                    float* __restrict__ part)
{
    int s = blockIdx.x >> 4;            // d-slab 0..15
    int t = (blockIdx.x & 15) * 256 + threadIdx.x;
    float sum = 0.f;
    int d0 = s * 32;
    #pragma unroll 8
    for (int d = d0; d < d0 + 32; ++d) {
        float v = V[(size_t)d * MB + t];
        sum += v * v;
    }
    part[(size_t)s * MB + t] = sum;
}

// ---- V normalize + emit Bt' (col-major [hi|lo|hi]) + WXt V-half, per d-slab ----
__global__ __launch_bounds__(256) void k_norm_V2(const float* __restrict__ V,
                                                 const float* __restrict__ part,
                                                 unsigned short* __restrict__ Btbf,
                                                 unsigned short* __restrict__ WXt)
{
    int s = blockIdx.x >> 4;
    int t = (blockIdx.x & 15) * 256 + threadIdx.x;
    float n2 = 0.f;
    #pragma unroll
    for (int i = 0; i < 16; ++i) n2 += part[(size_t)i * MB + t];
    float inv = 1.0f / fmaxf(sqrtf(n2), EPSV);
    size_t row = (size_t)t * KTOT;
    int dbeg = s * 32;
    for (int d0 = dbeg; d0 < dbeg + 32; d0 += 8) {
        ushort8 hi, lo;
        #pragma unroll
        for (int j = 0; j < 8; ++j) {
            float f = V[(size_t)(d0 + j) * MB + t] * inv;
            unsigned short h = f2b(f);
            hi[j] = h;
            lo[j] = f2b(f - b2f(h));
            WXt[(size_t)(512 + d0 + j) * MB + t] = h;
        }
        *(ushort8*)&Btbf[row + d0]        = hi;
        *(ushort8*)&Btbf[row + 512 + d0]  = lo;
        *(ushort8*)&Btbf[row + 1024 + d0] = hi;
    }
}

// ---- U column-norm partials over p axis (513 rows; slab 15 takes the tail) ----
__global__ __launch_bounds__(256) void k_unorm_part(const float* __restrict__ U,
                                                    float* __restrict__ part)
{
    int s = blockIdx.x >> 4;
    int t = (blockIdx.x & 15) * 256 + threadIdx.x;
    int m = t >> 3, b = t & 7;
    size_t base = (size_t)m * UROW + b;
    int pbeg = s * 32;
    int pend = (s == 15) ? 513 : pbeg + 32;
    float sum = 0.f;
    for (int p = pbeg; p < pend; ++p) {
        float u = U[base + (size_t)p * 8];
        sum += u * u;
    }
    part[(size_t)s * MB + t] = sum;
}

// ---- U normalize + emit WXt U-half (row p, entry t) + U2t[t*512+p], per p-slab ----
__global__ __launch_bounds__(256) void k_norm_U2(const float* __restrict__ U,
                                                 const float* __restrict__ part,
                                                 unsigned short* __restrict__ WXt,
                                                 unsigned short* __restrict__ U2t)
{
    int s = blockIdx.x >> 4;
    int t = (blockIdx.x & 15) * 256 + threadIdx.x;
    int m = t >> 3, b = t & 7;
    size_t base = (size_t)m * UROW + b;
    float n2 = 0.f;
    #pragma unroll
    for (int i = 0; i < 16; ++i) n2 += part[(size_t)i * MB + t];
    float inv = 1.0f / fmaxf(sqrtf(n2), EPSV);
    int pbeg = s * 32;
    for (int p0 = pbeg; p0 < pbeg + 32; p0 += 8) {
        ushort8 h8;
        #pragma unroll
        for (int j = 0; j < 8; ++j) {
            unsigned short h = f2b(U[base + (size_t)(p0 + j) * 8] * inv);
            h8[j] = h;
            WXt[(size_t)(p0 + j) * MB + t] = h;
        }
        *(ushort8*)&U2t[(size_t)t * D_DIM + p0] = h8;
    }
}

// ---------------- generic m97-style bf16 GEMM ----------------
// A row-major (rows x KDIM), Bt col-major (Bt[col*KDIM + k]), output 4096 x (NCB*NT)
// OUTMODE 0: C fp32.  1: C fp32 + bf16 Cb for col<512 (ld 512).  2: Cb bf16 only.
template<int MT, int NT, int KDIM, int LDC, int NCB, int OUTMODE>
__global__ __launch_bounds__(256) void k_gemm_t(const unsigned short* __restrict__ A,
                                                const unsigned short* __restrict__ Bt,
                                                float* __restrict__ C,
                                                unsigned short* __restrict__ Cb)
{
    __shared__ __align__(16) unsigned short As[MT * 64];
    __shared__ __align__(16) unsigned short Bs[NT * 64];

    constexpr int NWG  = (4096 / MT) * NCB;
    constexpr int AISS = MT / 32;
    constexpr int BISS = NT / 32;
    constexpr int MR   = MT / 32;     // per-wave m repeats (wave tile MT/2)
    constexpr int NR   = NT / 32;

    int tid = threadIdx.x;
    int wid = tid >> 6;
    int lane = tid & 63;

    int bid = blockIdx.x;
    int swz = (bid & 7) * (NWG >> 3) + (bid >> 3);
    int brow = (swz / NCB) * MT;
    int bcol = (swz % NCB) * NT;
    int wr = wid >> 1, wc = wid & 1;

    const unsigned short* aptr[AISS];
    const unsigned short* bptr[BISS];
    unsigned short* alds[AISS];
    unsigned short* blds[BISS];
    #pragma unroll
    for (int i = 0; i < AISS; ++i) {
        int q = wid * AISS + i;
        int r = q * 8 + (lane >> 3);
        aptr[i] = A + (size_t)(brow + r) * KDIM + (lane & 7) * 8;
        alds[i] = &As[q * 512];
    }
    #pragma unroll
    for (int i = 0; i < BISS; ++i) {
        int q = wid * BISS + i;
        int r = q * 8 + (lane >> 3);
        bptr[i] = Bt + (size_t)(bcol + r) * KDIM + (lane & 7) * 8;
        blds[i] = &Bs[q * 512];
    }

    int aofs0 = (wr * (MT / 2) + (lane & 15)) * 64 + (lane >> 4) * 8;
    int bofs0 = (wc * (NT / 2) + (lane & 15)) * 64 + (lane >> 4) * 8;

    f32x4 acc[MR][NR] = {};

    #pragma unroll
    for (int i = 0; i < AISS; ++i) gload_lds16(aptr[i], alds[i]);
    #pragma unroll
    for (int i = 0; i < BISS; ++i) gload_lds16(bptr[i], blds[i]);

    for (int t = 0; t < KDIM / 64; ++t) {
        __syncthreads();
        #pragma unroll
        for (int kc = 0; kc < 2; ++kc) {
            short8 af[MR], bf_[NR];
            #pragma unroll
            for (int m = 0; m < MR; ++m) af[m]  = *(const short8*)&As[aofs0 + m * 1024 + kc * 32];
            #pragma unroll
            for (int n = 0; n < NR; ++n) bf_[n] = *(const short8*)&Bs[bofs0 + n * 1024 + kc * 32];
            #pragma unroll
            for (int m = 0; m < MR; ++m)
                #pragma unroll
                for (int n = 0; n < NR; ++n)
                    acc[m][n] = __builtin_amdgcn_mfma_f32_16x16x32_bf16(
                        af[m], bf_[n], acc[m][n], 0, 0, 0);
        }
        __syncthreads();
        if (t + 1 < KDIM / 64) {
            int k0 = (t + 1) * 64;
            #pragma unroll
            for (int i = 0; i < AISS; ++i) gload_lds16(aptr[i] + k0, alds[i]);
            #pragma unroll
            for (int i = 0; i < BISS; ++i) gload_lds16(bptr[i] + k0, blds[i]);
        }
    }

    // C/D layout: col=lane&15, row=(lane>>4)*4+reg  [verified m89/m91]
    #pragma unroll
    for (int m = 0; m < MR; ++m) {
        int row0 = brow + wr * (MT / 2) + m * 16 + (lane >> 4) * 4;
        #pragma unroll
        for (int n = 0; n < NR; ++n) {
            int col = bcol + wc * (NT / 2) + n * 16 + (lane & 15);
            #pragma unroll
            for (int r = 0; r < 4; ++r) {
                float v = acc[m][n][r];
                int row = row0 + r;
                if (OUTMODE == 0) {
                    C[(size_t)row * LDC + col] = v;
                } else if (OUTMODE == 1) {
                    C[(size_t)row * LDC + col] = v;
                    if (col < 512) Cb[(size_t)row * 512 + col] = f2b(v);
                } else {
                    Cb[(size_t)row * LDC + col] = f2b(v);
                }
            }
        }
    }
}

// ---------- top-16 per token (one wave per token) + masked bf16 h emission ----------
__global__ __launch_bounds__(256) void k_topk(const float* __restrict__ h_all,
                                              int* __restrict__ topk_idx,
                                              int* __restrict__ counts,
                                              unsigned short* __restrict__ hb)
{
    int wave = threadIdx.x >> 6;
    int lane = threadIdx.x & 63;
    int n = blockIdx.x * 4 + wave;
    float ev[8];
    #pragma unroll
    for (int i = 0; i < 8; ++i) {
        int e = i * 64 + lane;
        const float4* hp = (const float4*)&h_all[(size_t)n * MB + e * 8];
        float4 a = hp[0], b = hp[1];
        ev[i] = a.x*a.x + a.y*a.y + a.z*a.z + a.w*a.w
              + b.x*b.x + b.y*b.y + b.z*b.z + b.w*b.w;
    }
    for (int r = 0; r < K_TOP; ++r) {
        float bv = -1.0f; int bi = 0;
        #pragma unroll
        for (int i = 0; i < 8; ++i) {
            if (ev[i] > bv) { bv = ev[i]; bi = i * 64 + lane; }
        }
        #pragma unroll
        for (int off = 1; off < 64; off <<= 1) {
            float ov = __shfl_xor(bv, off);
            int   oi = __shfl_xor(bi, off);
            if (ov > bv || (ov == bv && oi < bi)) { bv = ov; bi = oi; }
        }
        if (lane == 0) {
            topk_idx[n * K_TOP + r] = bi;
            atomicAdd(&counts[bi], 1);
        }
        #pragma unroll
        for (int i = 0; i < 8; ++i)
            if (((bi >> 6) == i) && (lane == (bi & 63))) ev[i] = -INFINITY;
    }
    // emit masked bf16 h row: selected experts keep h, others 0
    #pragma unroll
    for (int i = 0; i < 8; ++i) {
        int e = i * 64 + lane;
        const float4* hp = (const float4*)&h_all[(size_t)n * MB + e * 8];
        float4 a = hp[0], b = hp[1];
        bool sel = (ev[i] == -INFINITY);
        ushort8 o;
        o[0] = sel ? f2b(a.x) : 0;  o[1] = sel ? f2b(a.y) : 0;
        o[2] = sel ? f2b(a.z) : 0;  o[3] = sel ? f2b(a.w) : 0;
        o[4] = sel ? f2b(b.x) : 0;  o[5] = sel ? f2b(b.y) : 0;
        o[6] = sel ? f2b(b.z) : 0;  o[7] = sel ? f2b(b.w) : 0;
        *(ushort8*)&hb[(size_t)n * MB + e * 8] = o;
    }
}

// ---------- token-major finalize: x_out, uncap, writer (one wave per token) ----------
__global__ __launch_bounds__(256) void k_fin_tok(const float* __restrict__ xn,
                                                 const float* __restrict__ wx,
                                                 const unsigned short* __restrict__ hrecon,
                                                 const float* __restrict__ h_all,
                                                 const int* __restrict__ topk_idx,
                                                 float* __restrict__ x_out,
                                                 float* __restrict__ uncap,
                                                 float* __restrict__ writer)
{
    int wave = threadIdx.x >> 6;
    int lane = threadIdx.x & 63;
    int n = blockIdx.x * 4 + wave;

    const float4* xp = (const float4*)&xn[(size_t)n * D_DIM + lane * 8];
    const float4* wp = (const float4*)&wx[(size_t)n * 1024 + lane * 8];
    const float4* ap = (const float4*)&wx[(size_t)n * 1024 + 512 + lane * 8];
    float4 x0 = xp[0], x1 = xp[1];
    float4 w0 = wp[0], w1 = wp[1];
    float4 a0 = ap[0], a1 = ap[1];
    float y[8] = {x0.x+w0.x, x0.y+w0.y, x0.z+w0.z, x0.w+w0.w,
                  x1.x+w1.x, x1.y+w1.y, x1.z+w1.z, x1.w+w1.w};
    float r[8] = {x0.x-a0.x, x0.y-a0.y, x0.z-a0.z, x0.w-a0.w,
                  x1.x-a1.x, x1.y-a1.y, x1.z-a1.z, x1.w-a1.w};
    float s1 = 0.f, s2 = 0.f;
    #pragma unroll
    for (int j = 0; j < 8; ++j) { s1 += r[j]*r[j]; s2 += y[j]*y[j]; }
    #pragma unroll
    for (int off = 1; off < 64; off <<= 1) {
        s1 += __shfl_xor(s1, off);
        s2 += __shfl_xor(s2, off);
    }
    float inv = 1.0f / fmaxf(sqrtf(s2), EPSV);
    float4* op = (float4*)&x_out[(size_t)n * D_DIM + lane * 8];
    op[0] = make_float4(y[0]*inv, y[1]*inv, y[2]*inv, y[3]*inv);
    op[1] = make_float4(y[4]*inv, y[5]*inv, y[6]*inv, y[7]*inv);

    // writer part: 128 (k,b) pairs, 2 per lane
    float acc = 0.f;
    #pragma unroll
    for (int pp = 0; pp < 2; ++pp) {
        int p = lane + pp * 64;
        int m = topk_idx[n * K_TOP + (p >> 3)];
        size_t id = (size_t)n * MB + m * 8 + (p & 7);
        float d = b2f(hrecon[id]) - h_all[id];
        acc += d * d;
    }
    #pragma unroll
    for (int off = 1; off < 64; off <<= 1) acc += __shfl_xor(acc, off);
    if (lane == 0) { uncap[n] = s1; writer[n] = acc; }
}

// ---------------- final scalar reductions + counts ----------------
__global__ __launch_bounds__(256) void k_finalize(const float* __restrict__ uncap,
                                                  const float* __restrict__ writer,
                                                  const int* __restrict__ counts,
                                                  float* __restrict__ out)
{
    __shared__ float ru[256], rw[256];
    int t = threadIdx.x;
    float su = 0.f, sw = 0.f;
    for (int i = t; i < N_TOK; i += 256) { su += uncap[i]; sw += writer[i]; }
    ru[t] = su; rw[t] = sw;
    __syncthreads();
    for (int s = 128; s > 0; s >>= 1) {
        if (t < s) { ru[t] += ru[t + s]; rw[t] += rw[t + s]; }
        __syncthreads();
    }
    if (t == 0)
        out[(size_t)N_TOK * D_DIM] = ru[0] / (float)N_TOK
                                   + rw[0] / (float)(N_TOK * K_TOP * B_DIM);
    for (int i = t; i < M_EXP; i += 256)
        out[(size_t)N_TOK * D_DIM + 1 + i] = (float)counts[i];
}

extern "C" void kernel_launch(void* const* d_in, const int* in_sizes, int n_in,
                              void* d_out, int out_size, void* d_ws, size_t ws_size,
                              hipStream_t stream)
{
    const float* x = (const float*)d_in[0];
    const float* V = (const float*)d_in[1];
    const float* U = (const float*)d_in[2];
    float* out = (float*)d_out;

    float* ws     = (float*)d_ws;
    float* xn     = ws;                        // 2,097,152 f   (8.4 MB)
    float* h_all  = xn + 2097152;              // 16,777,216 f  (67.1 MB)
    float* wx     = h_all + 16777216;          // 4,194,304 f   (16.8 MB) writes|xhat
    float* uncap  = wx + 4194304;              // 4096 f
    float* writer = uncap + 4096;              // 4096 f
    int*   topk_i = (int*)(writer + 4096);     // 65,536 i
    int*   counts = topk_i + 65536;            // 512 i  (+pad 512)
    float* partV  = (float*)(counts + 1024);   // 65,536 f (16 x 4096)
    float* partU  = partV + 65536;             // 65,536 f
    unsigned short* U2t     = (unsigned short*)(partU + 65536);  // 2,097,152 us (4.2 MB)
    unsigned short* WXt     = U2t + 2097152;   // 4,194,304 us (8.4 MB)
    unsigned short* writesb = WXt + 4194304;   // 2,097,152 us (4.2 MB)
    unsigned short* R       = writesb + 2097152; // 16,777,216 us (33.6 MB) shared region
    unsigned short* Abf     = R;               // 6,291,456 us  (gemm1 A')
    unsigned short* Btbf    = R + 6291456;     // 6,291,456 us  (gemm1 B')
    unsigned short* hb      = R;               // 16,777,216 us (after gemm1)
    unsigned short* hrecon  = R;               // 16,777,216 us (after gemm23)
    // total ws use ~144 MB

    hipMemsetAsync(counts, 0, M_EXP * sizeof(int), stream);
    k_norm_x    <<<N_TOK / 4, 256, 0, stream>>>(x, xn, Abf);
    k_vnorm_part<<<256, 256, 0, stream>>>(V, partV);
    k_norm_V2   <<<256, 256, 0, stream>>>(V, partV, Btbf, WXt);
    k_unorm_part<<<256, 256, 0, stream>>>(U, partU);
    k_norm_U2   <<<256, 256, 0, stream>>>(U, partU, WXt, U2t);
    // GEMM1: h_all = A'(4096x1536) @ B'(1536x4096), split-bf16, fp32 out
    k_gemm_t<128, 128, KTOT, 4096, 32, 0><<<1024, 256, 0, stream>>>(Abf, Btbf, h_all, nullptr);
    k_topk      <<<N_TOK / 4, 256, 0, stream>>>(h_all, topk_i, counts, hb);
    // GEMM23: wx = hb(4096x4096) @ WXt^T -> (4096x1024) [writes|xhat], + writesb bf16
    k_gemm_t<128, 64, 4096, 1024, 16, 1><<<512, 256, 0, stream>>>(hb, WXt, wx, writesb);
    // GEMM4: hrecon = writesb(4096x512) @ U2t^T -> (4096x4096) bf16
    k_gemm_t<128, 128, 512, 4096, 32, 2><<<1024, 256, 0, stream>>>(writesb, U2t, nullptr, hrecon);
    k_fin_tok   <<<N_TOK / 4, 256, 0, stream>>>(xn, wx, hrecon, h_all, topk_i, out, uncap, writer);
    k_finalize  <<<1, 256, 0, stream>>>(uncap, writer, counts, out);
}

// Round 6
// 262.958 us; speedup vs baseline: 2.5527x; 1.0744x over previous
//
#include <hip/hip_runtime.h>
#include <math.h>

#define N_TOK 4096
#define D_DIM 512
#define M_EXP 512
#define B_DIM 8
#define K_TOP 16
#define MB    4096          // M_EXP * B_DIM
#define UROW  4104          // (D_DIM+1) * B_DIM
#define EPSV  1e-8f
#define KTOT  1536          // 3 * D (split-bf16 K blocks for GEMM1)

typedef unsigned short ushort8 __attribute__((ext_vector_type(8)));
typedef short short8 __attribute__((ext_vector_type(8)));
typedef float f32x4 __attribute__((ext_vector_type(4)));

__device__ inline float b2f(unsigned short u) {
    union { unsigned int i; float f; } c;
    c.i = ((unsigned int)u) << 16;
    return c.f;
}
__device__ inline unsigned short f2b(float f) {     // RNE bf16
    union { float f; unsigned int i; } c; c.f = f;
    unsigned int lsb = (c.i >> 16) & 1;
    c.i += 0x7fffu + lsb;
    return (unsigned short)(c.i >> 16);
}
__device__ inline void gload_lds16(const unsigned short* g, unsigned short* l) {
    __builtin_amdgcn_global_load_lds(
        (const __attribute__((address_space(1))) unsigned int*)g,
        (__attribute__((address_space(3))) unsigned int*)l, 16, 0, 0);
}

// ------------- normalize x rows; emit xn fp32 + A' = [hi|hi|lo] bf16 -------------
__global__ __launch_bounds__(256) void k_norm_x(const float* __restrict__ x,
                                                float* __restrict__ xn,
                                                unsigned short* __restrict__ Abf)
{
    int wave = threadIdx.x >> 6;
    int lane = threadIdx.x & 63;
    int n = blockIdx.x * 4 + wave;
    const float4* xp = (const float4*)&x[(size_t)n * D_DIM + lane * 8];
    float4 a = xp[0], b = xp[1];
    float s = a.x*a.x + a.y*a.y + a.z*a.z + a.w*a.w
            + b.x*b.x + b.y*b.y + b.z*b.z + b.w*b.w;
    #pragma unroll
    for (int off = 1; off < 64; off <<= 1) s += __shfl_xor(s, off);
    float inv = 1.0f / fmaxf(sqrtf(s), EPSV);
    float v[8] = {a.x*inv, a.y*inv, a.z*inv, a.w*inv,
                  b.x*inv, b.y*inv, b.z*inv, b.w*inv};
    float4* op = (float4*)&xn[(size_t)n * D_DIM + lane * 8];
    op[0] = make_float4(v[0], v[1], v[2], v[3]);
    op[1] = make_float4(v[4], v[5], v[6], v[7]);
    ushort8 hi, lo;
    #pragma unroll
    for (int j = 0; j < 8; ++j) {
        unsigned short h = f2b(v[j]);
        hi[j] = h;
        lo[j] = f2b(v[j] - b2f(h));
    }
    size_t base = (size_t)n * KTOT + lane * 8;
    *(ushort8*)&Abf[base]        = hi;
    *(ushort8*)&Abf[base + 512]  = hi;
    *(ushort8*)&Abf[base + 1024] = lo;
}

// ---- V column-norm partials: part[s][t] = sum_{d in slab s (32 rows)} V[d][t]^2 ----
__global__ __launch_bounds__(256) void k_vnorm_part(const float* __restrict__ V,
                                                    float* __restrict__ part)
{
    int s = blockIdx.x >> 4;            // d-slab 0..15
    int t = (blockIdx.x & 15) * 256 + threadIdx.x;
    float sum = 0.f;
    int d0 = s * 32;
    #pragma unroll 8
    for (int d = d0; d < d0 + 32; ++d) {
        float v = V[(size_t)d * MB + t];
        sum += v * v;
    }
    part[(size_t)s * MB + t] = sum;
}

// ---- V normalize + emit Bt' (col-major [hi|lo|hi]) + WXt V-half, per d-slab ----
__global__ __launch_bounds__(256) void k_norm_V2(const float* __restrict__ V,
                                                 const float* __restrict__ part,
                                                 unsigned short* __restrict__ Btbf,
                                                 unsigned short* __restrict__ WXt)
{
    int s = blockIdx.x >> 4;
    int t = (blockIdx.x & 15) * 256 + threadIdx.x;
    float n2 = 0.f;
    #pragma unroll
    for (int i = 0; i < 16; ++i) n2 += part[(size_t)i * MB + t];
    float inv = 1.0f / fmaxf(sqrtf(n2), EPSV);
    size_t row = (size_t)t * KTOT;
    int dbeg = s * 32;
    for (int d0 = dbeg; d0 < dbeg + 32; d0 += 8) {
        ushort8 hi, lo;
        #pragma unroll
        for (int j = 0; j < 8; ++j) {
            float f = V[(size_t)(d0 + j) * MB + t] * inv;
            unsigned short h = f2b(f);
            hi[j] = h;
            lo[j] = f2b(f - b2f(h));
            WXt[(size_t)(512 + d0 + j) * MB + t] = h;
        }
        *(ushort8*)&Btbf[row + d0]        = hi;
        *(ushort8*)&Btbf[row + 512 + d0]  = lo;
        *(ushort8*)&Btbf[row + 1024 + d0] = hi;
    }
}

// ---- U column-norm partials over p axis (513 rows; slab 15 takes the tail) ----
__global__ __launch_bounds__(256) void k_unorm_part(const float* __restrict__ U,
                                                    float* __restrict__ part)
{
    int s = blockIdx.x >> 4;
    int t = (blockIdx.x & 15) * 256 + threadIdx.x;
    int m = t >> 3, b = t & 7;
    size_t base = (size_t)m * UROW + b;
    int pbeg = s * 32;
    int pend = (s == 15) ? 513 : pbeg + 32;
    float sum = 0.f;
    for (int p = pbeg; p < pend; ++p) {
        float u = U[base + (size_t)p * 8];
        sum += u * u;
    }
    part[(size_t)s * MB + t] = sum;
}

// ---- U normalize + emit WXt U-half (row p, entry t) + U2t[t*512+p], per p-slab ----
__global__ __launch_bounds__(256) void k_norm_U2(const float* __restrict__ U,
                                                 const float* __restrict__ part,
                                                 unsigned short* __restrict__ WXt,
                                                 unsigned short* __restrict__ U2t)
{
    int s = blockIdx.x >> 4;
    int t = (blockIdx.x & 15) * 256 + threadIdx.x;
    int m = t >> 3, b = t & 7;
    size_t base = (size_t)m * UROW + b;
    float n2 = 0.f;
    #pragma unroll
    for (int i = 0; i < 16; ++i) n2 += part[(size_t)i * MB + t];
    float inv = 1.0f / fmaxf(sqrtf(n2), EPSV);
    int pbeg = s * 32;
    for (int p0 = pbeg; p0 < pbeg + 32; p0 += 8) {
        ushort8 h8;
        #pragma unroll
        for (int j = 0; j < 8; ++j) {
            unsigned short h = f2b(U[base + (size_t)(p0 + j) * 8] * inv);
            h8[j] = h;
            WXt[(size_t)(p0 + j) * MB + t] = h;
        }
        *(ushort8*)&U2t[(size_t)t * D_DIM + p0] = h8;
    }
}

// ================== 8-phase 256x256 bf16 GEMM (T3+T4+T5, k-slot swizzle) ==================
// A row-major (4096 x KDIM), Bt col-major (Bt[col*KDIM + k]), C 4096x4096.
// LDS: lds[buf][op][kc][row*32 + k], unit (buf,op,kc) = 16KB staged by 2 gload_lds16/thread.
// k-slot swizzle: LDS elem (row*32 + k8*8+u) holds global k = (k8 ^ (row&3))*8 + u.
template<int KDIM, int BUF, int KC, int MH, bool READB, int SBUF, int SOP, int SKC, bool DOVM>
__device__ __forceinline__ void gemm_phase(const unsigned short* __restrict__ A,
                                           const unsigned short* __restrict__ Bt,
                                           unsigned short (*lds)[2][2][8192],
                                           f32x4 (&acc)[8][4], short8 (&bfr)[4],
                                           int wr, int wc, int lane, int wid,
                                           int brow, int bcol, int stile)
{
    const unsigned short* aun = lds[BUF][0][KC];
    const unsigned short* bun = lds[BUF][1][KC];
    int ko = ((lane >> 4) ^ (lane & 3)) * 8;     // swizzled k-slot for this lane
    short8 af[4];
    #pragma unroll
    for (int mi = 0; mi < 4; ++mi) {
        int rowL = wr * 128 + (MH * 4 + mi) * 16 + (lane & 15);
        af[mi] = *(const short8*)&aun[rowL * 32 + ko];
    }
    if (READB) {
        #pragma unroll
        for (int ni = 0; ni < 4; ++ni) {
            int colL = wc * 64 + ni * 16 + (lane & 15);
            bfr[ni] = *(const short8*)&bun[colL * 32 + ko];
        }
    }
    // stage one unit (pre-swizzled global source, linear LDS dest)
    {
        const unsigned short* src = SOP ? Bt : A;
        int rbase = SOP ? bcol : brow;
        #pragma unroll
        for (int j = 0; j < 2; ++j) {
            int c = wid * 128 + j * 64 + lane;
            int row = c >> 2, k8 = c & 3;
            int k8s = k8 ^ (row & 3);
            const unsigned short* gp = src + (size_t)(rbase + row) * KDIM
                                     + stile * 64 + SKC * 32 + k8s * 8;
            unsigned short* lp = lds[SBUF][SOP][SKC] + (wid * 128 + j * 64) * 8;
            gload_lds16(gp, lp);
        }
    }
    __builtin_amdgcn_sched_barrier(0);
    __builtin_amdgcn_s_barrier();
    asm volatile("s_waitcnt lgkmcnt(0)" ::: "memory");
    __builtin_amdgcn_sched_barrier(0);
    __builtin_amdgcn_s_setprio(1);
    #pragma unroll
    for (int mi = 0; mi < 4; ++mi)
        #pragma unroll
        for (int ni = 0; ni < 4; ++ni)
            acc[MH * 4 + mi][ni] = __builtin_amdgcn_mfma_f32_16x16x32_bf16(
                af[mi], bfr[ni], acc[MH * 4 + mi][ni], 0, 0, 0);
    __builtin_amdgcn_s_setprio(0);
    if (DOVM) asm volatile("s_waitcnt vmcnt(8)" ::: "memory");
    __builtin_amdgcn_sched_barrier(0);
    __builtin_amdgcn_s_barrier();
    __builtin_amdgcn_sched_barrier(0);
}

// OUTMODE 0: C fp32 (LDC 4096).  2: Cb bf16 (LDC 4096).
template<int KDIM, int OUTMODE>
__global__ __launch_bounds__(512, 1) void k_gemm8(const unsigned short* __restrict__ A,
                                                  const unsigned short* __restrict__ Bt,
                                                  float* __restrict__ C,
                                                  unsigned short* __restrict__ Cb)
{
    __shared__ unsigned short lds[2][2][2][8192];   // 128 KiB

    constexpr int KT  = KDIM / 64;
    constexpr int NIT = KDIM / 128;

    int tid = threadIdx.x;
    int wid = tid >> 6;
    int lane = tid & 63;
    int wr = wid >> 2, wc = wid & 3;

    int bid = blockIdx.x;                   // 256 wg, 256 % 8 == 0 -> bijective
    int swz = (bid & 7) * 32 + (bid >> 3);
    int brow = (swz >> 4) * 256;
    int bcol = (swz & 15) * 256;

    f32x4 acc[8][4] = {};
    short8 bfr[4];

    // ---- prologue: stage tile0 (4 units) + tile1.kc0 (2 units) ----
    auto stage0 = [&](int sbuf, int sop, int skc, int stile) {
        const unsigned short* src = sop ? Bt : A;
        int rbase = sop ? bcol : brow;
        #pragma unroll
        for (int j = 0; j < 2; ++j) {
            int c = wid * 128 + j * 64 + lane;
            int row = c >> 2, k8 = c & 3;
            int k8s = k8 ^ (row & 3);
            const unsigned short* gp = src + (size_t)(rbase + row) * KDIM
                                     + stile * 64 + skc * 32 + k8s * 8;
            unsigned short* lp = lds[sbuf][sop][skc] + (wid * 128 + j * 64) * 8;
            gload_lds16(gp, lp);
        }
    };
    stage0(0, 0, 0, 0); stage0(0, 1, 0, 0);
    stage0(0, 0, 1, 0); stage0(0, 1, 1, 0);
    stage0(1, 0, 0, 1); stage0(1, 1, 0, 1);
    asm volatile("s_waitcnt vmcnt(8)" ::: "memory");
    __builtin_amdgcn_sched_barrier(0);
    __builtin_amdgcn_s_barrier();
    __builtin_amdgcn_sched_barrier(0);

    for (int i = 0; i < NIT; ++i) {
        int t1 = 2 * i + 1; if (t1 > KT - 1) t1 = KT - 1;
        int t2 = 2 * i + 2; if (t2 > KT - 1) t2 = KT - 1;
        int t3 = 2 * i + 3; if (t3 > KT - 1) t3 = KT - 1;
        // ph1..ph8: compute tiles 2i (buf0) and 2i+1 (buf1); stage per derived schedule
        gemm_phase<KDIM, 0, 0, 0, true , 1, 0, 1, false>(A, Bt, lds, acc, bfr, wr, wc, lane, wid, brow, bcol, t1);
        gemm_phase<KDIM, 0, 0, 1, false, 1, 1, 1, true >(A, Bt, lds, acc, bfr, wr, wc, lane, wid, brow, bcol, t1);
        gemm_phase<KDIM, 0, 1, 0, true , 0, 0, 0, false>(A, Bt, lds, acc, bfr, wr, wc, lane, wid, brow, bcol, t2);
        gemm_phase<KDIM, 0, 1, 1, false, 0, 1, 0, true >(A, Bt, lds, acc, bfr, wr, wc, lane, wid, brow, bcol, t2);
        gemm_phase<KDIM, 1, 0, 0, true , 0, 0, 1, false>(A, Bt, lds, acc, bfr, wr, wc, lane, wid, brow, bcol, t2);
        gemm_phase<KDIM, 1, 0, 1, false, 0, 1, 1, true >(A, Bt, lds, acc, bfr, wr, wc, lane, wid, brow, bcol, t2);
        gemm_phase<KDIM, 1, 1, 0, true , 1, 0, 0, false>(A, Bt, lds, acc, bfr, wr, wc, lane, wid, brow, bcol, t3);
        gemm_phase<KDIM, 1, 1, 1, false, 1, 1, 0, true >(A, Bt, lds, acc, bfr, wr, wc, lane, wid, brow, bcol, t3);
    }

    // epilogue: C/D layout col=lane&15, row=(lane>>4)*4+reg  [verified m89/m91]
    #pragma unroll
    for (int mr = 0; mr < 8; ++mr) {
        int row0 = brow + wr * 128 + mr * 16 + (lane >> 4) * 4;
        #pragma unroll
        for (int nr = 0; nr < 4; ++nr) {
            int col = bcol + wc * 64 + nr * 16 + (lane & 15);
            #pragma unroll
            for (int r = 0; r < 4; ++r) {
                if (OUTMODE == 0)
                    C[(size_t)(row0 + r) * 4096 + col] = acc[mr][nr][r];
                else
                    Cb[(size_t)(row0 + r) * 4096 + col] = f2b(acc[mr][nr][r]);
            }
        }
    }
}

// ---------------- m97-style bf16 GEMM (kept for GEMM23) ----------------
template<int MT, int NT, int KDIM, int LDC, int NCB, int OUTMODE>
__global__ __launch_bounds__(256) void k_gemm_t(const unsigned short* __restrict__ A,
                                                const unsigned short* __restrict__ Bt,
                                                float* __restrict__ C,
                                                unsigned short* __restrict__ Cb)
{
    __shared__ __align__(16) unsigned short As[MT * 64];
    __shared__ __align__(16) unsigned short Bs[NT * 64];

    constexpr int NWG  = (4096 / MT) * NCB;
    constexpr int AISS = MT / 32;
    constexpr int BISS = NT / 32;
    constexpr int MR   = MT / 32;
    constexpr int NR   = NT / 32;

    int tid = threadIdx.x;
    int wid = tid >> 6;
    int lane = tid & 63;

    int bid = blockIdx.x;
    int swz = (bid & 7) * (NWG >> 3) + (bid >> 3);
    int brow = (swz / NCB) * MT;
    int bcol = (swz % NCB) * NT;
    int wr = wid >> 1, wc = wid & 1;

    const unsigned short* aptr[AISS];
    const unsigned short* bptr[BISS];
    unsigned short* alds[AISS];
    unsigned short* blds[BISS];
    #pragma unroll
    for (int i = 0; i < AISS; ++i) {
        int q = wid * AISS + i;
        int r = q * 8 + (lane >> 3);
        aptr[i] = A + (size_t)(brow + r) * KDIM + (lane & 7) * 8;
        alds[i] = &As[q * 512];
    }
    #pragma unroll
    for (int i = 0; i < BISS; ++i) {
        int q = wid * BISS + i;
        int r = q * 8 + (lane >> 3);
        bptr[i] = Bt + (size_t)(bcol + r) * KDIM + (lane & 7) * 8;
        blds[i] = &Bs[q * 512];
    }

    int aofs0 = (wr * (MT / 2) + (lane & 15)) * 64 + (lane >> 4) * 8;
    int bofs0 = (wc * (NT / 2) + (lane & 15)) * 64 + (lane >> 4) * 8;

    f32x4 acc[MR][NR] = {};

    #pragma unroll
    for (int i = 0; i < AISS; ++i) gload_lds16(aptr[i], alds[i]);
    #pragma unroll
    for (int i = 0; i < BISS; ++i) gload_lds16(bptr[i], blds[i]);

    for (int t = 0; t < KDIM / 64; ++t) {
        __syncthreads();
        #pragma unroll
        for (int kc = 0; kc < 2; ++kc) {
            short8 af[MR], bf_[NR];
            #pragma unroll
            for (int m = 0; m < MR; ++m) af[m]  = *(const short8*)&As[aofs0 + m * 1024 + kc * 32];
            #pragma unroll
            for (int n = 0; n < NR; ++n) bf_[n] = *(const short8*)&Bs[bofs0 + n * 1024 + kc * 32];
            #pragma unroll
            for (int m = 0; m < MR; ++m)
                #pragma unroll
                for (int n = 0; n < NR; ++n)
                    acc[m][n] = __builtin_amdgcn_mfma_f32_16x16x32_bf16(
                        af[m], bf_[n], acc[m][n], 0, 0, 0);
        }
        __syncthreads();
        if (t + 1 < KDIM / 64) {
            int k0 = (t + 1) * 64;
            #pragma unroll
            for (int i = 0; i < AISS; ++i) gload_lds16(aptr[i] + k0, alds[i]);
            #pragma unroll
            for (int i = 0; i < BISS; ++i) gload_lds16(bptr[i] + k0, blds[i]);
        }
    }

    #pragma unroll
    for (int m = 0; m < MR; ++m) {
        int row0 = brow + wr * (MT / 2) + m * 16 + (lane >> 4) * 4;
        #pragma unroll
        for (int n = 0; n < NR; ++n) {
            int col = bcol + wc * (NT / 2) + n * 16 + (lane & 15);
            #pragma unroll
            for (int r = 0; r < 4; ++r) {
                float v = acc[m][n][r];
                int row = row0 + r;
                if (OUTMODE == 0) {
                    C[(size_t)row * LDC + col] = v;
                } else if (OUTMODE == 1) {
                    C[(size_t)row * LDC + col] = v;
                    if (col < 512) Cb[(size_t)row * 512 + col] = f2b(v);
                } else {
                    Cb[(size_t)row * LDC + col] = f2b(v);
                }
            }
        }
    }
}

// ---------- top-16 per token (one wave per token) + masked bf16 h emission ----------
__global__ __launch_bounds__(256) void k_topk(const float* __restrict__ h_all,
                                              int* __restrict__ topk_idx,
                                              int* __restrict__ counts,
                                              unsigned short* __restrict__ hb)
{
    int wave = threadIdx.x >> 6;
    int lane = threadIdx.x & 63;
    int n = blockIdx.x * 4 + wave;
    float ev[8];
    #pragma unroll
    for (int i = 0; i < 8; ++i) {
        int e = i * 64 + lane;
        const float4* hp = (const float4*)&h_all[(size_t)n * MB + e * 8];
        float4 a = hp[0], b = hp[1];
        ev[i] = a.x*a.x + a.y*a.y + a.z*a.z + a.w*a.w
              + b.x*b.x + b.y*b.y + b.z*b.z + b.w*b.w;
    }
    for (int r = 0; r < K_TOP; ++r) {
        float bv = -1.0f; int bi = 0;
        #pragma unroll
        for (int i = 0; i < 8; ++i) {
            if (ev[i] > bv) { bv = ev[i]; bi = i * 64 + lane; }
        }
        #pragma unroll
        for (int off = 1; off < 64; off <<= 1) {
            float ov = __shfl_xor(bv, off);
            int   oi = __shfl_xor(bi, off);
            if (ov > bv || (ov == bv && oi < bi)) { bv = ov; bi = oi; }
        }
        if (lane == 0) {
            topk_idx[n * K_TOP + r] = bi;
            atomicAdd(&counts[bi], 1);
        }
        #pragma unroll
        for (int i = 0; i < 8; ++i)
            if (((bi >> 6) == i) && (lane == (bi & 63))) ev[i] = -INFINITY;
    }
    // emit masked bf16 h row: selected experts keep h, others 0
    #pragma unroll
    for (int i = 0; i < 8; ++i) {
        int e = i * 64 + lane;
        const float4* hp = (const float4*)&h_all[(size_t)n * MB + e * 8];
        float4 a = hp[0], b = hp[1];
        bool sel = (ev[i] == -INFINITY);
        ushort8 o;
        o[0] = sel ? f2b(a.x) : 0;  o[1] = sel ? f2b(a.y) : 0;
        o[2] = sel ? f2b(a.z) : 0;  o[3] = sel ? f2b(a.w) : 0;
        o[4] = sel ? f2b(b.x) : 0;  o[5] = sel ? f2b(b.y) : 0;
        o[6] = sel ? f2b(b.z) : 0;  o[7] = sel ? f2b(b.w) : 0;
        *(ushort8*)&hb[(size_t)n * MB + e * 8] = o;
    }
}

// ---------- token-major finalize: x_out, uncap, writer (one wave per token) ----------
__global__ __launch_bounds__(256) void k_fin_tok(const float* __restrict__ xn,
                                                 const float* __restrict__ wx,
                                                 const unsigned short* __restrict__ hrecon,
                                                 const float* __restrict__ h_all,
                                                 const int* __restrict__ topk_idx,
                                                 float* __restrict__ x_out,
                                                 float* __restrict__ uncap,
                                                 float* __restrict__ writer)
{
    int wave = threadIdx.x >> 6;
    int lane = threadIdx.x & 63;
    int n = blockIdx.x * 4 + wave;

    const float4* xp = (const float4*)&xn[(size_t)n * D_DIM + lane * 8];
    const float4* wp = (const float4*)&wx[(size_t)n * 1024 + lane * 8];
    const float4* ap = (const float4*)&wx[(size_t)n * 1024 + 512 + lane * 8];
    float4 x0 = xp[0], x1 = xp[1];
    float4 w0 = wp[0], w1 = wp[1];
    float4 a0 = ap[0], a1 = ap[1];
    float y[8] = {x0.x+w0.x, x0.y+w0.y, x0.z+w0.z, x0.w+w0.w,
                  x1.x+w1.x, x1.y+w1.y, x1.z+w1.z, x1.w+w1.w};
    float r[8] = {x0.x-a0.x, x0.y-a0.y, x0.z-a0.z, x0.w-a0.w,
                  x1.x-a1.x, x1.y-a1.y, x1.z-a1.z, x1.w-a1.w};
    float s1 = 0.f, s2 = 0.f;
    #pragma unroll
    for (int j = 0; j < 8; ++j) { s1 += r[j]*r[j]; s2 += y[j]*y[j]; }
    #pragma unroll
    for (int off = 1; off < 64; off <<= 1) {
        s1 += __shfl_xor(s1, off);
        s2 += __shfl_xor(s2, off);
    }
    float inv = 1.0f / fmaxf(sqrtf(s2), EPSV);
    float4* op = (float4*)&x_out[(size_t)n * D_DIM + lane * 8];
    op[0] = make_float4(y[0]*inv, y[1]*inv, y[2]*inv, y[3]*inv);
    op[1] = make_float4(y[4]*inv, y[5]*inv, y[6]*inv, y[7]*inv);

    float acc = 0.f;
    #pragma unroll
    for (int pp = 0; pp < 2; ++pp) {
        int p = lane + pp * 64;
        int m = topk_idx[n * K_TOP + (p >> 3)];
        size_t id = (size_t)n * MB + m * 8 + (p & 7);
        float d = b2f(hrecon[id]) - h_all[id];
        acc += d * d;
    }
    #pragma unroll
    for (int off = 1; off < 64; off <<= 1) acc += __shfl_xor(acc, off);
    if (lane == 0) { uncap[n] = s1; writer[n] = acc; }
}

// ---------------- final scalar reductions + counts ----------------
__global__ __launch_bounds__(256) void k_finalize(const float* __restrict__ uncap,
                                                  const float* __restrict__ writer,
                                                  const int* __restrict__ counts,
                                                  float* __restrict__ out)
{
    __shared__ float ru[256], rw[256];
    int t = threadIdx.x;
    float su = 0.f, sw = 0.f;
    for (int i = t; i < N_TOK; i += 256) { su += uncap[i]; sw += writer[i]; }
    ru[t] = su; rw[t] = sw;
    __syncthreads();
    for (int s = 128; s > 0; s >>= 1) {
        if (t < s) { ru[t] += ru[t + s]; rw[t] += rw[t + s]; }
        __syncthreads();
    }
    if (t == 0)
        out[(size_t)N_TOK * D_DIM] = ru[0] / (float)N_TOK
                                   + rw[0] / (float)(N_TOK * K_TOP * B_DIM);
    for (int i = t; i < M_EXP; i += 256)
        out[(size_t)N_TOK * D_DIM + 1 + i] = (float)counts[i];
}

extern "C" void kernel_launch(void* const* d_in, const int* in_sizes, int n_in,
                              void* d_out, int out_size, void* d_ws, size_t ws_size,
                              hipStream_t stream)
{
    const float* x = (const float*)d_in[0];
    const float* V = (const float*)d_in[1];
    const float* U = (const float*)d_in[2];
    float* out = (float*)d_out;

    float* ws     = (float*)d_ws;
    float* xn     = ws;                        // 2,097,152 f   (8.4 MB)
    float* h_all  = xn + 2097152;              // 16,777,216 f  (67.1 MB)
    float* wx     = h_all + 16777216;          // 4,194,304 f   (16.8 MB) writes|xhat
    float* uncap  = wx + 4194304;              // 4096 f
    float* writer = uncap + 4096;              // 4096 f
    int*   topk_i = (int*)(writer + 4096);     // 65,536 i
    int*   counts = topk_i + 65536;            // 512 i  (+pad 512)
    float* partV  = (float*)(counts + 1024);   // 65,536 f (16 x 4096)
    float* partU  = partV + 65536;             // 65,536 f
    unsigned short* U2t     = (unsigned short*)(partU + 65536);  // 2,097,152 us (4.2 MB)
    unsigned short* WXt     = U2t + 2097152;   // 4,194,304 us (8.4 MB)
    unsigned short* writesb = WXt + 4194304;   // 2,097,152 us (4.2 MB)
    unsigned short* R       = writesb + 2097152; // 16,777,216 us (33.6 MB) shared region
    unsigned short* Abf     = R;               // 6,291,456 us  (gemm1 A')
    unsigned short* Btbf    = R + 6291456;     // 6,291,456 us  (gemm1 B')
    unsigned short* hb      = R;               // 16,777,216 us (after gemm1)
    unsigned short* hrecon  = R;               // 16,777,216 us (after gemm23)
    // total ws use ~144 MB

    hipMemsetAsync(counts, 0, M_EXP * sizeof(int), stream);
    k_norm_x    <<<N_TOK / 4, 256, 0, stream>>>(x, xn, Abf);
    k_vnorm_part<<<256, 256, 0, stream>>>(V, partV);
    k_norm_V2   <<<256, 256, 0, stream>>>(V, partV, Btbf, WXt);
    k_unorm_part<<<256, 256, 0, stream>>>(U, partU);
    k_norm_U2   <<<256, 256, 0, stream>>>(U, partU, WXt, U2t);
    // GEMM1: h_all = A'(4096x1536) @ B'(1536x4096), split-bf16, 8-phase 256^2
    k_gemm8<KTOT, 0><<<256, 512, 0, stream>>>(Abf, Btbf, h_all, nullptr);
    k_topk      <<<N_TOK / 4, 256, 0, stream>>>(h_all, topk_i, counts, hb);
    // GEMM23: wx = hb(4096x4096) @ WXt^T -> (4096x1024) [writes|xhat], + writesb bf16
    k_gemm_t<128, 64, 4096, 1024, 16, 1><<<512, 256, 0, stream>>>(hb, WXt, wx, writesb);
    // GEMM4: hrecon = writesb(4096x512) @ U2t^T -> (4096x4096) bf16, 8-phase 256^2
    k_gemm8<D_DIM, 2><<<256, 512, 0, stream>>>(writesb, U2t, nullptr, hrecon);
    k_fin_tok   <<<N_TOK / 4, 256, 0, stream>>>(xn, wx, hrecon, h_all, topk_i, out, uncap, writer);
    k_finalize  <<<1, 256, 0, stream>>>(uncap, writer, counts, out);
}

// Round 7
// 243.731 us; speedup vs baseline: 2.7540x; 1.0789x over previous
//
#include <hip/hip_runtime.h>
#include <math.h>

#define N_TOK 4096
#define D_DIM 512
#define M_EXP 512
#define B_DIM 8
#define K_TOP 16
#define MB    4096          // M_EXP * B_DIM
#define UROW  4104          // (D_DIM+1) * B_DIM
#define EPSV  1e-8f
#define KTOT  1536          // 3 * D (split-bf16 K blocks for GEMM1)

typedef unsigned short ushort8 __attribute__((ext_vector_type(8)));
typedef unsigned short ushort4v __attribute__((ext_vector_type(4)));
typedef short short8 __attribute__((ext_vector_type(8)));
typedef float f32x4 __attribute__((ext_vector_type(4)));

__device__ inline float b2f(unsigned short u) {
    union { unsigned int i; float f; } c;
    c.i = ((unsigned int)u) << 16;
    return c.f;
}
__device__ inline unsigned short f2b(float f) {     // RNE bf16
    union { float f; unsigned int i; } c; c.f = f;
    unsigned int lsb = (c.i >> 16) & 1;
    c.i += 0x7fffu + lsb;
    return (unsigned short)(c.i >> 16);
}
__device__ inline void gload_lds16(const unsigned short* g, unsigned short* l) {
    __builtin_amdgcn_global_load_lds(
        (const __attribute__((address_space(1))) unsigned int*)g,
        (__attribute__((address_space(3))) unsigned int*)l, 16, 0, 0);
}

// ------------- normalize x rows; emit xn fp32 + A' = [hi|hi|lo] bf16 -------------
__global__ __launch_bounds__(256) void k_norm_x(const float* __restrict__ x,
                                                float* __restrict__ xn,
                                                unsigned short* __restrict__ Abf)
{
    int wave = threadIdx.x >> 6;
    int lane = threadIdx.x & 63;
    int n = blockIdx.x * 4 + wave;
    const float4* xp = (const float4*)&x[(size_t)n * D_DIM + lane * 8];
    float4 a = xp[0], b = xp[1];
    float s = a.x*a.x + a.y*a.y + a.z*a.z + a.w*a.w
            + b.x*b.x + b.y*b.y + b.z*b.z + b.w*b.w;
    #pragma unroll
    for (int off = 1; off < 64; off <<= 1) s += __shfl_xor(s, off);
    float inv = 1.0f / fmaxf(sqrtf(s), EPSV);
    float v[8] = {a.x*inv, a.y*inv, a.z*inv, a.w*inv,
                  b.x*inv, b.y*inv, b.z*inv, b.w*inv};
    float4* op = (float4*)&xn[(size_t)n * D_DIM + lane * 8];
    op[0] = make_float4(v[0], v[1], v[2], v[3]);
    op[1] = make_float4(v[4], v[5], v[6], v[7]);
    ushort8 hi, lo;
    #pragma unroll
    for (int j = 0; j < 8; ++j) {
        unsigned short h = f2b(v[j]);
        hi[j] = h;
        lo[j] = f2b(v[j] - b2f(h));
    }
    size_t base = (size_t)n * KTOT + lane * 8;
    *(ushort8*)&Abf[base]        = hi;
    *(ushort8*)&Abf[base + 512]  = hi;
    *(ushort8*)&Abf[base + 1024] = lo;
}

// ---- V column-norm partials: part[s][t] = sum_{d in slab s (32 rows)} V[d][t]^2 ----
__global__ __launch_bounds__(256) void k_vnorm_part(const float* __restrict__ V,
                                                    float* __restrict__ part)
{
    int s = blockIdx.x >> 4;            // d-slab 0..15
    int t = (blockIdx.x & 15) * 256 + threadIdx.x;
    float sum = 0.f;
    int d0 = s * 32;
    #pragma unroll 8
    for (int d = d0; d < d0 + 32; ++d) {
        float v = V[(size_t)d * MB + t];
        sum += v * v;
    }
    part[(size_t)s * MB + t] = sum;
}

// ---- V normalize + emit Bt' (col-major [hi|lo|hi]) + WXt V-half, per d-slab ----
__global__ __launch_bounds__(256) void k_norm_V2(const float* __restrict__ V,
                                                 const float* __restrict__ part,
                                                 unsigned short* __restrict__ Btbf,
                                                 unsigned short* __restrict__ WXt)
{
    int s = blockIdx.x >> 4;
    int t = (blockIdx.x & 15) * 256 + threadIdx.x;
    float n2 = 0.f;
    #pragma unroll
    for (int i = 0; i < 16; ++i) n2 += part[(size_t)i * MB + t];
    float inv = 1.0f / fmaxf(sqrtf(n2), EPSV);
    size_t row = (size_t)t * KTOT;
    int dbeg = s * 32;
    for (int d0 = dbeg; d0 < dbeg + 32; d0 += 8) {
        ushort8 hi, lo;
        #pragma unroll
        for (int j = 0; j < 8; ++j) {
            float f = V[(size_t)(d0 + j) * MB + t] * inv;
            unsigned short h = f2b(f);
            hi[j] = h;
            lo[j] = f2b(f - b2f(h));
            WXt[(size_t)(512 + d0 + j) * MB + t] = h;
        }
        *(ushort8*)&Btbf[row + d0]        = hi;
        *(ushort8*)&Btbf[row + 512 + d0]  = lo;
        *(ushort8*)&Btbf[row + 1024 + d0] = hi;
    }
}

// ---- U column-norm partials over p axis (513 rows; slab 15 takes the tail) ----
__global__ __launch_bounds__(256) void k_unorm_part(const float* __restrict__ U,
                                                    float* __restrict__ part)
{
    int s = blockIdx.x >> 4;
    int t = (blockIdx.x & 15) * 256 + threadIdx.x;
    int m = t >> 3, b = t & 7;
    size_t base = (size_t)m * UROW + b;
    int pbeg = s * 32;
    int pend = (s == 15) ? 513 : pbeg + 32;
    float sum = 0.f;
    for (int p = pbeg; p < pend; ++p) {
        float u = U[base + (size_t)p * 8];
        sum += u * u;
    }
    part[(size_t)s * MB + t] = sum;
}

// ---- U normalize + emit WXt U-half (row p, entry t) + U2t[t*512+p], per p-slab ----
__global__ __launch_bounds__(256) void k_norm_U2(const float* __restrict__ U,
                                                 const float* __restrict__ part,
                                                 unsigned short* __restrict__ WXt,
                                                 unsigned short* __restrict__ U2t)
{
    int s = blockIdx.x >> 4;
    int t = (blockIdx.x & 15) * 256 + threadIdx.x;
    int m = t >> 3, b = t & 7;
    size_t base = (size_t)m * UROW + b;
    float n2 = 0.f;
    #pragma unroll
    for (int i = 0; i < 16; ++i) n2 += part[(size_t)i * MB + t];
    float inv = 1.0f / fmaxf(sqrtf(n2), EPSV);
    int pbeg = s * 32;
    for (int p0 = pbeg; p0 < pbeg + 32; p0 += 8) {
        ushort8 h8;
        #pragma unroll
        for (int j = 0; j < 8; ++j) {
            unsigned short h = f2b(U[base + (size_t)(p0 + j) * 8] * inv);
            h8[j] = h;
            WXt[(size_t)(p0 + j) * MB + t] = h;
        }
        *(ushort8*)&U2t[(size_t)t * D_DIM + p0] = h8;
    }
}

// ================== 8-phase 256x256 bf16 GEMM (T3+T4+T5, k-slot swizzle) ==================
// A row-major (4096 x KROW), Bt col-major (Bt[col*KROW + k]).
// LDS: lds[buf][op][kc][row*32 + k], unit (buf,op,kc) = 16KB staged by 2 gload_lds16/thread.
// k-slot swizzle: LDS elem (row*32 + k8*8+u) holds global k = (k8 ^ (row&3))*8 + u.
template<int KROW, int BUF, int KC, int MH, bool READB, int SBUF, int SOP, int SKC, bool DOVM>
__device__ __forceinline__ void gemm_phase(const unsigned short* __restrict__ A,
                                           const unsigned short* __restrict__ Bt,
                                           unsigned short (*lds)[2][2][8192],
                                           f32x4 (&acc)[8][4], short8 (&bfr)[4],
                                           int wr, int wc, int lane, int wid,
                                           int brow, int bcol, int stile)
{
    const unsigned short* aun = lds[BUF][0][KC];
    const unsigned short* bun = lds[BUF][1][KC];
    int ko = ((lane >> 4) ^ (lane & 3)) * 8;     // swizzled k-slot for this lane
    short8 af[4];
    #pragma unroll
    for (int mi = 0; mi < 4; ++mi) {
        int rowL = wr * 128 + (MH * 4 + mi) * 16 + (lane & 15);
        af[mi] = *(const short8*)&aun[rowL * 32 + ko];
    }
    if (READB) {
        #pragma unroll
        for (int ni = 0; ni < 4; ++ni) {
            int colL = wc * 64 + ni * 16 + (lane & 15);
            bfr[ni] = *(const short8*)&bun[colL * 32 + ko];
        }
    }
    // stage one unit (pre-swizzled global source, linear LDS dest)
    {
        const unsigned short* src = SOP ? Bt : A;
        int rbase = SOP ? bcol : brow;
        #pragma unroll
        for (int j = 0; j < 2; ++j) {
            int c = wid * 128 + j * 64 + lane;
            int row = c >> 2, k8 = c & 3;
            int k8s = k8 ^ (row & 3);
            const unsigned short* gp = src + (size_t)(rbase + row) * KROW
                                     + stile * 64 + SKC * 32 + k8s * 8;
            unsigned short* lp = lds[SBUF][SOP][SKC] + (wid * 128 + j * 64) * 8;
            gload_lds16(gp, lp);
        }
    }
    __builtin_amdgcn_sched_barrier(0);
    __builtin_amdgcn_s_barrier();
    asm volatile("s_waitcnt lgkmcnt(0)" ::: "memory");
    __builtin_amdgcn_sched_barrier(0);
    __builtin_amdgcn_s_setprio(1);
    #pragma unroll
    for (int mi = 0; mi < 4; ++mi)
        #pragma unroll
        for (int ni = 0; ni < 4; ++ni)
            acc[MH * 4 + mi][ni] = __builtin_amdgcn_mfma_f32_16x16x32_bf16(
                af[mi], bfr[ni], acc[MH * 4 + mi][ni], 0, 0, 0);
    __builtin_amdgcn_s_setprio(0);
    if (DOVM) asm volatile("s_waitcnt vmcnt(8)" ::: "memory");
    __builtin_amdgcn_sched_barrier(0);
    __builtin_amdgcn_s_barrier();
    __builtin_amdgcn_sched_barrier(0);
}

// KROW: row stride of A and Bt; KLEN: K extent per wg (split-K slice); NCOLT: output
// 256-col tiles; SPLITK: slices (partial slabs of 4096*LDC fp32 each, concatenated);
// OUTMODE 0: C fp32.  2: Cb bf16.
template<int KROW, int KLEN, int NCOLT, int SPLITK, int LDC, int OUTMODE>
__global__ __launch_bounds__(512, 1) void k_gemm8(const unsigned short* __restrict__ A,
                                                  const unsigned short* __restrict__ Bt,
                                                  float* __restrict__ C,
                                                  unsigned short* __restrict__ Cb)
{
    __shared__ unsigned short lds[2][2][2][8192];   // 128 KiB

    constexpr int KT   = KLEN / 64;
    constexpr int NIT  = KLEN / 128;
    constexpr int ROWT = 16;                        // 4096 / 256
    constexpr int NWG  = ROWT * NCOLT * SPLITK;     // must be % 8 == 0

    int tid = threadIdx.x;
    int wid = tid >> 6;
    int lane = tid & 63;
    int wr = wid >> 2, wc = wid & 3;

    int bid = blockIdx.x;
    int swz = (bid & 7) * (NWG / 8) + (bid >> 3);
    int ks   = swz / (ROWT * NCOLT);
    int tile = swz % (ROWT * NCOLT);
    int brow = (tile / NCOLT) * 256;
    int bcol = (tile % NCOLT) * 256;

    const unsigned short* Aofs = A + (size_t)ks * KLEN;
    const unsigned short* Bofs = Bt + (size_t)ks * KLEN;
    float* Cofs = C + (size_t)ks * 4096 * LDC;

    f32x4 acc[8][4] = {};
    short8 bfr[4];

    // ---- prologue: stage tile0 (4 units) + tile1.kc0 (2 units) ----
    auto stage0 = [&](int sbuf, int sop, int skc, int stile) {
        const unsigned short* src = sop ? Bofs : Aofs;
        int rbase = sop ? bcol : brow;
        #pragma unroll
        for (int j = 0; j < 2; ++j) {
            int c = wid * 128 + j * 64 + lane;
            int row = c >> 2, k8 = c & 3;
            int k8s = k8 ^ (row & 3);
            const unsigned short* gp = src + (size_t)(rbase + row) * KROW
                                     + stile * 64 + skc * 32 + k8s * 8;
            unsigned short* lp = lds[sbuf][sop][skc] + (wid * 128 + j * 64) * 8;
            gload_lds16(gp, lp);
        }
    };
    stage0(0, 0, 0, 0); stage0(0, 1, 0, 0);
    stage0(0, 0, 1, 0); stage0(0, 1, 1, 0);
    stage0(1, 0, 0, 1); stage0(1, 1, 0, 1);
    asm volatile("s_waitcnt vmcnt(8)" ::: "memory");
    __builtin_amdgcn_sched_barrier(0);
    __builtin_amdgcn_s_barrier();
    __builtin_amdgcn_sched_barrier(0);

    for (int i = 0; i < NIT; ++i) {
        int t1 = 2 * i + 1; if (t1 > KT - 1) t1 = KT - 1;
        int t2 = 2 * i + 2; if (t2 > KT - 1) t2 = KT - 1;
        int t3 = 2 * i + 3; if (t3 > KT - 1) t3 = KT - 1;
        gemm_phase<KROW, 0, 0, 0, true , 1, 0, 1, false>(Aofs, Bofs, lds, acc, bfr, wr, wc, lane, wid, brow, bcol, t1);
        gemm_phase<KROW, 0, 0, 1, false, 1, 1, 1, true >(Aofs, Bofs, lds, acc, bfr, wr, wc, lane, wid, brow, bcol, t1);
        gemm_phase<KROW, 0, 1, 0, true , 0, 0, 0, false>(Aofs, Bofs, lds, acc, bfr, wr, wc, lane, wid, brow, bcol, t2);
        gemm_phase<KROW, 0, 1, 1, false, 0, 1, 0, true >(Aofs, Bofs, lds, acc, bfr, wr, wc, lane, wid, brow, bcol, t2);
        gemm_phase<KROW, 1, 0, 0, true , 0, 0, 1, false>(Aofs, Bofs, lds, acc, bfr, wr, wc, lane, wid, brow, bcol, t2);
        gemm_phase<KROW, 1, 0, 1, false, 0, 1, 1, true >(Aofs, Bofs, lds, acc, bfr, wr, wc, lane, wid, brow, bcol, t2);
        gemm_phase<KROW, 1, 1, 0, true , 1, 0, 0, false>(Aofs, Bofs, lds, acc, bfr, wr, wc, lane, wid, brow, bcol, t3);
        gemm_phase<KROW, 1, 1, 1, false, 1, 1, 0, true >(Aofs, Bofs, lds, acc, bfr, wr, wc, lane, wid, brow, bcol, t3);
    }

    // epilogue: C/D layout col=lane&15, row=(lane>>4)*4+reg  [verified m89/m91]
    #pragma unroll
    for (int mr = 0; mr < 8; ++mr) {
        int row0 = brow + wr * 128 + mr * 16 + (lane >> 4) * 4;
        #pragma unroll
        for (int nr = 0; nr < 4; ++nr) {
            int col = bcol + wc * 64 + nr * 16 + (lane & 15);
            #pragma unroll
            for (int r = 0; r < 4; ++r) {
                if (OUTMODE == 0)
                    Cofs[(size_t)(row0 + r) * LDC + col] = acc[mr][nr][r];
                else
                    Cb[(size_t)(row0 + r) * LDC + col] = f2b(acc[mr][nr][r]);
            }
        }
    }
}

// ---- reduce 4 split-K partials -> wx fp32 (4096x1024) + writesb bf16 (cols<512) ----
__global__ __launch_bounds__(256) void k_reduce4(const float* __restrict__ P,
                                                 float* __restrict__ wx,
                                                 unsigned short* __restrict__ wb)
{
    const size_t S = (size_t)4096 * 1024;
    int g = blockIdx.x * 256 + threadIdx.x;        // float4 index, total 1048576
    float4 a = ((const float4*)P)[g];
    float4 b = ((const float4*)(P + S))[g];
    float4 c = ((const float4*)(P + 2 * S))[g];
    float4 d = ((const float4*)(P + 3 * S))[g];
    float4 v = make_float4(a.x + b.x + c.x + d.x, a.y + b.y + c.y + d.y,
                           a.z + b.z + c.z + d.z, a.w + b.w + c.w + d.w);
    ((float4*)wx)[g] = v;
    int c4 = g & 255;
    if (c4 < 128) {
        int row = g >> 8;
        ushort4v o;
        o[0] = f2b(v.x); o[1] = f2b(v.y); o[2] = f2b(v.z); o[3] = f2b(v.w);
        *(ushort4v*)&wb[(size_t)row * 512 + c4 * 4] = o;
    }
}

// ---- top-16 per token + masked bf16 h emission + compact fp32 h_sel (n,128) ----
__global__ __launch_bounds__(256) void k_topk(const float* __restrict__ h_all,
                                              int* __restrict__ topk_idx,
                                              int* __restrict__ counts,
                                              unsigned short* __restrict__ hb,
                                              float* __restrict__ h_sel)
{
    int wave = threadIdx.x >> 6;
    int lane = threadIdx.x & 63;
    int n = blockIdx.x * 4 + wave;
    float ev[8];
    #pragma unroll
    for (int i = 0; i < 8; ++i) {
        int e = i * 64 + lane;
        const float4* hp = (const float4*)&h_all[(size_t)n * MB + e * 8];
        float4 a = hp[0], b = hp[1];
        ev[i] = a.x*a.x + a.y*a.y + a.z*a.z + a.w*a.w
              + b.x*b.x + b.y*b.y + b.z*b.z + b.w*b.w;
    }
    for (int r = 0; r < K_TOP; ++r) {
        float bv = -1.0f; int bi = 0;
        #pragma unroll
        for (int i = 0; i < 8; ++i) {
            if (ev[i] > bv) { bv = ev[i]; bi = i * 64 + lane; }
        }
        #pragma unroll
        for (int off = 1; off < 64; off <<= 1) {
            float ov = __shfl_xor(bv, off);
            int   oi = __shfl_xor(bi, off);
            if (ov > bv || (ov == bv && oi < bi)) { bv = ov; bi = oi; }
        }
        if (lane == 0) {
            topk_idx[n * K_TOP + r] = bi;
            atomicAdd(&counts[bi], 1);
        }
        // compact copy of the selected expert's fp32 h values (cache-hot re-read)
        if (lane < 8)
            h_sel[(size_t)n * 128 + r * 8 + lane] = h_all[(size_t)n * MB + bi * 8 + lane];
        #pragma unroll
        for (int i = 0; i < 8; ++i)
            if (((bi >> 6) == i) && (lane == (bi & 63))) ev[i] = -INFINITY;
    }
    // emit masked bf16 h row: selected experts keep h, others 0
    #pragma unroll
    for (int i = 0; i < 8; ++i) {
        int e = i * 64 + lane;
        const float4* hp = (const float4*)&h_all[(size_t)n * MB + e * 8];
        float4 a = hp[0], b = hp[1];
        bool sel = (ev[i] == -INFINITY);
        ushort8 o;
        o[0] = sel ? f2b(a.x) : 0;  o[1] = sel ? f2b(a.y) : 0;
        o[2] = sel ? f2b(a.z) : 0;  o[3] = sel ? f2b(a.w) : 0;
        o[4] = sel ? f2b(b.x) : 0;  o[5] = sel ? f2b(b.y) : 0;
        o[6] = sel ? f2b(b.z) : 0;  o[7] = sel ? f2b(b.w) : 0;
        *(ushort8*)&hb[(size_t)n * MB + e * 8] = o;
    }
}

// ---------- token-major finalize: x_out, uncap, writer (one wave per token) ----------
__global__ __launch_bounds__(256) void k_fin_tok(const float* __restrict__ xn,
                                                 const float* __restrict__ wx,
                                                 const unsigned short* __restrict__ hrecon,
                                                 const float* __restrict__ h_sel,
                                                 const int* __restrict__ topk_idx,
                                                 float* __restrict__ x_out,
                                                 float* __restrict__ uncap,
                                                 float* __restrict__ writer)
{
    int wave = threadIdx.x >> 6;
    int lane = threadIdx.x & 63;
    int n = blockIdx.x * 4 + wave;

    const float4* xp = (const float4*)&xn[(size_t)n * D_DIM + lane * 8];
    const float4* wp = (const float4*)&wx[(size_t)n * 1024 + lane * 8];
    const float4* ap = (const float4*)&wx[(size_t)n * 1024 + 512 + lane * 8];
    float4 x0 = xp[0], x1 = xp[1];
    float4 w0 = wp[0], w1 = wp[1];
    float4 a0 = ap[0], a1 = ap[1];
    float y[8] = {x0.x+w0.x, x0.y+w0.y, x0.z+w0.z, x0.w+w0.w,
                  x1.x+w1.x, x1.y+w1.y, x1.z+w1.z, x1.w+w1.w};
    float r[8] = {x0.x-a0.x, x0.y-a0.y, x0.z-a0.z, x0.w-a0.w,
                  x1.x-a1.x, x1.y-a1.y, x1.z-a1.z, x1.w-a1.w};
    float s1 = 0.f, s2 = 0.f;
    #pragma unroll
    for (int j = 0; j < 8; ++j) { s1 += r[j]*r[j]; s2 += y[j]*y[j]; }
    #pragma unroll
    for (int off = 1; off < 64; off <<= 1) {
        s1 += __shfl_xor(s1, off);
        s2 += __shfl_xor(s2, off);
    }
    float inv = 1.0f / fmaxf(sqrtf(s2), EPSV);
    float4* op = (float4*)&x_out[(size_t)n * D_DIM + lane * 8];
    op[0] = make_float4(y[0]*inv, y[1]*inv, y[2]*inv, y[3]*inv);
    op[1] = make_float4(y[4]*inv, y[5]*inv, y[6]*inv, y[7]*inv);

    float acc = 0.f;
    #pragma unroll
    for (int pp = 0; pp < 2; ++pp) {
        int p = lane + pp * 64;
        int m = topk_idx[n * K_TOP + (p >> 3)];
        float d = b2f(hrecon[(size_t)n * MB + m * 8 + (p & 7)])
                - h_sel[(size_t)n * 128 + p];
        acc += d * d;
    }
    #pragma unroll
    for (int off = 1; off < 64; off <<= 1) acc += __shfl_xor(acc, off);
    if (lane == 0) { uncap[n] = s1; writer[n] = acc; }
}

// ---------------- final scalar reductions + counts ----------------
__global__ __launch_bounds__(256) void k_finalize(const float* __restrict__ uncap,
                                                  const float* __restrict__ writer,
                                                  const int* __restrict__ counts,
                                                  float* __restrict__ out)
{
    __shared__ float ru[256], rw[256];
    int t = threadIdx.x;
    float su = 0.f, sw = 0.f;
    for (int i = t; i < N_TOK; i += 256) { su += uncap[i]; sw += writer[i]; }
    ru[t] = su; rw[t] = sw;
    __syncthreads();
    for (int s = 128; s > 0; s >>= 1) {
        if (t < s) { ru[t] += ru[t + s]; rw[t] += rw[t + s]; }
        __syncthreads();
    }
    if (t == 0)
        out[(size_t)N_TOK * D_DIM] = ru[0] / (float)N_TOK
                                   + rw[0] / (float)(N_TOK * K_TOP * B_DIM);
    for (int i = t; i < M_EXP; i += 256)
        out[(size_t)N_TOK * D_DIM + 1 + i] = (float)counts[i];
}

extern "C" void kernel_launch(void* const* d_in, const int* in_sizes, int n_in,
                              void* d_out, int out_size, void* d_ws, size_t ws_size,
                              hipStream_t stream)
{
    const float* x = (const float*)d_in[0];
    const float* V = (const float*)d_in[1];
    const float* U = (const float*)d_in[2];
    float* out = (float*)d_out;

    float* ws     = (float*)d_ws;
    float* xn     = ws;                        // 2,097,152 f   (8.4 MB)
    float* h_all  = xn + 2097152;              // 16,777,216 f  (67.1 MB); after topk,
                                               //   reused as 4 split-K partial slabs
    float* wx     = h_all + 16777216;          // 4,194,304 f   (16.8 MB) writes|xhat
    float* uncap  = wx + 4194304;              // 4096 f
    float* writer = uncap + 4096;              // 4096 f
    int*   topk_i = (int*)(writer + 4096);     // 65,536 i
    int*   counts = topk_i + 65536;            // 512 i  (+pad 512)
    float* partV  = (float*)(counts + 1024);   // 65,536 f (16 x 4096)
    float* partU  = partV + 65536;             // 65,536 f
    float* h_sel  = partU + 65536;             // 524,288 f (2.1 MB)
    unsigned short* U2t     = (unsigned short*)(h_sel + 524288); // 2,097,152 us (4.2 MB)
    unsigned short* WXt     = U2t + 2097152;   // 4,194,304 us (8.4 MB)
    unsigned short* writesb = WXt + 4194304;   // 2,097,152 us (4.2 MB)
    unsigned short* R       = writesb + 2097152; // 16,777,216 us (33.6 MB) shared region
    unsigned short* Abf     = R;               // 6,291,456 us  (gemm1 A')
    unsigned short* Btbf    = R + 6291456;     // 6,291,456 us  (gemm1 B')
    unsigned short* hb      = R;               // 16,777,216 us (after gemm1)
    unsigned short* hrecon  = R;               // 16,777,216 us (after gemm23+reduce)
    // total ws use ~146 MB

    hipMemsetAsync(counts, 0, M_EXP * sizeof(int), stream);
    k_norm_x    <<<N_TOK / 4, 256, 0, stream>>>(x, xn, Abf);
    k_vnorm_part<<<256, 256, 0, stream>>>(V, partV);
    k_norm_V2   <<<256, 256, 0, stream>>>(V, partV, Btbf, WXt);
    k_unorm_part<<<256, 256, 0, stream>>>(U, partU);
    k_norm_U2   <<<256, 256, 0, stream>>>(U, partU, WXt, U2t);
    // GEMM1: h_all = A'(4096x1536) @ B'(1536x4096), split-bf16, 8-phase 256^2
    k_gemm8<KTOT, KTOT, 16, 1, 4096, 0><<<256, 512, 0, stream>>>(Abf, Btbf, h_all, nullptr);
    k_topk      <<<N_TOK / 4, 256, 0, stream>>>(h_all, topk_i, counts, hb, h_sel);
    // GEMM23: wx_partial[ks] = hb(4096x4096, K-slice ks) @ WXt^T -> 4x(4096x1024)
    //         partial slabs alias h_all (dead after topk: fin_tok uses h_sel)
    k_gemm8<4096, 1024, 4, 4, 1024, 0><<<256, 512, 0, stream>>>(hb, WXt, h_all, nullptr);
    k_reduce4   <<<4096, 256, 0, stream>>>(h_all, wx, writesb);
    // GEMM4: hrecon = writesb(4096x512) @ U2t^T -> (4096x4096) bf16, 8-phase 256^2
    k_gemm8<D_DIM, D_DIM, 16, 1, 4096, 2><<<256, 512, 0, stream>>>(writesb, U2t, nullptr, hrecon);
    k_fin_tok   <<<N_TOK / 4, 256, 0, stream>>>(xn, wx, hrecon, h_sel, topk_i, out, uncap, writer);
    k_finalize  <<<1, 256, 0, stream>>>(uncap, writer, counts, out);
}

// Round 8
// 233.504 us; speedup vs baseline: 2.8747x; 1.0438x over previous
//
#include <hip/hip_runtime.h>
#include <math.h>

#define N_TOK 4096
#define D_DIM 512
#define M_EXP 512
#define B_DIM 8
#define K_TOP 16
#define MB    4096          // M_EXP * B_DIM
#define UROW  4104          // (D_DIM+1) * B_DIM
#define EPSV  1e-8f
#define KTOT  1536          // 3 * D (split-bf16 K blocks for GEMM1)

typedef unsigned short ushort8 __attribute__((ext_vector_type(8)));
typedef unsigned short ushort4v __attribute__((ext_vector_type(4)));
typedef short short8 __attribute__((ext_vector_type(8)));
typedef float f32x4 __attribute__((ext_vector_type(4)));

__device__ inline float b2f(unsigned short u) {
    union { unsigned int i; float f; } c;
    c.i = ((unsigned int)u) << 16;
    return c.f;
}
__device__ inline unsigned short f2b(float f) {     // RNE bf16
    union { float f; unsigned int i; } c; c.f = f;
    unsigned int lsb = (c.i >> 16) & 1;
    c.i += 0x7fffu + lsb;
    return (unsigned short)(c.i >> 16);
}
__device__ inline void gload_lds16(const unsigned short* g, unsigned short* l) {
    __builtin_amdgcn_global_load_lds(
        (const __attribute__((address_space(1))) unsigned int*)g,
        (__attribute__((address_space(3))) unsigned int*)l, 16, 0, 0);
}

// ------------- normalize x rows; emit xn fp32 + A' = [hi|hi|lo] bf16 -------------
__global__ __launch_bounds__(256) void k_norm_x(const float* __restrict__ x,
                                                float* __restrict__ xn,
                                                unsigned short* __restrict__ Abf)
{
    int wave = threadIdx.x >> 6;
    int lane = threadIdx.x & 63;
    int n = blockIdx.x * 4 + wave;
    const float4* xp = (const float4*)&x[(size_t)n * D_DIM + lane * 8];
    float4 a = xp[0], b = xp[1];
    float s = a.x*a.x + a.y*a.y + a.z*a.z + a.w*a.w
            + b.x*b.x + b.y*b.y + b.z*b.z + b.w*b.w;
    #pragma unroll
    for (int off = 1; off < 64; off <<= 1) s += __shfl_xor(s, off);
    float inv = 1.0f / fmaxf(sqrtf(s), EPSV);
    float v[8] = {a.x*inv, a.y*inv, a.z*inv, a.w*inv,
                  b.x*inv, b.y*inv, b.z*inv, b.w*inv};
    float4* op = (float4*)&xn[(size_t)n * D_DIM + lane * 8];
    op[0] = make_float4(v[0], v[1], v[2], v[3]);
    op[1] = make_float4(v[4], v[5], v[6], v[7]);
    ushort8 hi, lo;
    #pragma unroll
    for (int j = 0; j < 8; ++j) {
        unsigned short h = f2b(v[j]);
        hi[j] = h;
        lo[j] = f2b(v[j] - b2f(h));
    }
    size_t base = (size_t)n * KTOT + lane * 8;
    *(ushort8*)&Abf[base]        = hi;
    *(ushort8*)&Abf[base + 512]  = hi;
    *(ushort8*)&Abf[base + 1024] = lo;
}

// ---- V column-norm partials: part[s][t] = sum_{d in slab s (32 rows)} V[d][t]^2 ----
__global__ __launch_bounds__(256) void k_vnorm_part(const float* __restrict__ V,
                                                    float* __restrict__ part)
{
    int s = blockIdx.x >> 4;            // d-slab 0..15
    int t = (blockIdx.x & 15) * 256 + threadIdx.x;
    float sum = 0.f;
    int d0 = s * 32;
    #pragma unroll 8
    for (int d = d0; d < d0 + 32; ++d) {
        float v = V[(size_t)d * MB + t];
        sum += v * v;
    }
    part[(size_t)s * MB + t] = sum;
}

// ---- V normalize + emit Bt' (col-major [hi|lo|hi]) + WXt V-half, per d-slab ----
__global__ __launch_bounds__(256) void k_norm_V2(const float* __restrict__ V,
                                                 const float* __restrict__ part,
                                                 unsigned short* __restrict__ Btbf,
                                                 unsigned short* __restrict__ WXt)
{
    int s = blockIdx.x >> 4;
    int t = (blockIdx.x & 15) * 256 + threadIdx.x;
    float n2 = 0.f;
    #pragma unroll
    for (int i = 0; i < 16; ++i) n2 += part[(size_t)i * MB + t];
    float inv = 1.0f / fmaxf(sqrtf(n2), EPSV);
    size_t row = (size_t)t * KTOT;
    int dbeg = s * 32;
    for (int d0 = dbeg; d0 < dbeg + 32; d0 += 8) {
        ushort8 hi, lo;
        #pragma unroll
        for (int j = 0; j < 8; ++j) {
            float f = V[(size_t)(d0 + j) * MB + t] * inv;
            unsigned short h = f2b(f);
            hi[j] = h;
            lo[j] = f2b(f - b2f(h));
            WXt[(size_t)(512 + d0 + j) * MB + t] = h;
        }
        *(ushort8*)&Btbf[row + d0]        = hi;
        *(ushort8*)&Btbf[row + 512 + d0]  = lo;
        *(ushort8*)&Btbf[row + 1024 + d0] = hi;
    }
}

// ---- U column-norm partials over p axis (513 rows; slab 15 takes the tail) ----
__global__ __launch_bounds__(256) void k_unorm_part(const float* __restrict__ U,
                                                    float* __restrict__ part)
{
    int s = blockIdx.x >> 4;
    int t = (blockIdx.x & 15) * 256 + threadIdx.x;
    int m = t >> 3, b = t & 7;
    size_t base = (size_t)m * UROW + b;
    int pbeg = s * 32;
    int pend = (s == 15) ? 513 : pbeg + 32;
    float sum = 0.f;
    for (int p = pbeg; p < pend; ++p) {
        float u = U[base + (size_t)p * 8];
        sum += u * u;
    }
    part[(size_t)s * MB + t] = sum;
}

// ---- U normalize + emit WXt U-half (row p, entry t) + U2t[t*512+p], per p-slab ----
__global__ __launch_bounds__(256) void k_norm_U2(const float* __restrict__ U,
                                                 const float* __restrict__ part,
                                                 unsigned short* __restrict__ WXt,
                                                 unsigned short* __restrict__ U2t)
{
    int s = blockIdx.x >> 4;
    int t = (blockIdx.x & 15) * 256 + threadIdx.x;
    int m = t >> 3, b = t & 7;
    size_t base = (size_t)m * UROW + b;
    float n2 = 0.f;
    #pragma unroll
    for (int i = 0; i < 16; ++i) n2 += part[(size_t)i * MB + t];
    float inv = 1.0f / fmaxf(sqrtf(n2), EPSV);
    int pbeg = s * 32;
    for (int p0 = pbeg; p0 < pbeg + 32; p0 += 8) {
        ushort8 h8;
        #pragma unroll
        for (int j = 0; j < 8; ++j) {
            unsigned short h = f2b(U[base + (size_t)(p0 + j) * 8] * inv);
            h8[j] = h;
            WXt[(size_t)(p0 + j) * MB + t] = h;
        }
        *(ushort8*)&U2t[(size_t)t * D_DIM + p0] = h8;
    }
}

// ================== 8-phase 256x256 bf16 GEMM (T3+T4+T5, k-slot swizzle) ==================
// A row-major (4096 x KROW), Bt col-major (Bt[col*KROW + k]).
// LDS: lds[buf][op][kc][row*32 + k], unit (buf,op,kc) = 16KB staged by 2 gload_lds16/thread.
// k-slot swizzle: LDS elem (row*32 + k8*8+u) holds global k = (k8 ^ (row&3))*8 + u.
template<int KROW, int BUF, int KC, int MH, bool READB, int SBUF, int SOP, int SKC, bool DOVM>
__device__ __forceinline__ void gemm_phase(const unsigned short* __restrict__ A,
                                           const unsigned short* __restrict__ Bt,
                                           unsigned short (*lds)[2][2][8192],
                                           f32x4 (&acc)[8][4], short8 (&bfr)[4],
                                           int wr, int wc, int lane, int wid,
                                           int brow, int bcol, int stile)
{
    const unsigned short* aun = lds[BUF][0][KC];
    const unsigned short* bun = lds[BUF][1][KC];
    int ko = ((lane >> 4) ^ (lane & 3)) * 8;     // swizzled k-slot for this lane
    short8 af[4];
    #pragma unroll
    for (int mi = 0; mi < 4; ++mi) {
        int rowL = wr * 128 + (MH * 4 + mi) * 16 + (lane & 15);
        af[mi] = *(const short8*)&aun[rowL * 32 + ko];
    }
    if (READB) {
        #pragma unroll
        for (int ni = 0; ni < 4; ++ni) {
            int colL = wc * 64 + ni * 16 + (lane & 15);
            bfr[ni] = *(const short8*)&bun[colL * 32 + ko];
        }
    }
    // stage one unit (pre-swizzled global source, linear LDS dest)
    {
        const unsigned short* src = SOP ? Bt : A;
        int rbase = SOP ? bcol : brow;
        #pragma unroll
        for (int j = 0; j < 2; ++j) {
            int c = wid * 128 + j * 64 + lane;
            int row = c >> 2, k8 = c & 3;
            int k8s = k8 ^ (row & 3);
            const unsigned short* gp = src + (size_t)(rbase + row) * KROW
                                     + stile * 64 + SKC * 32 + k8s * 8;
            unsigned short* lp = lds[SBUF][SOP][SKC] + (wid * 128 + j * 64) * 8;
            gload_lds16(gp, lp);
        }
    }
    __builtin_amdgcn_sched_barrier(0);
    __builtin_amdgcn_s_barrier();
    asm volatile("s_waitcnt lgkmcnt(0)" ::: "memory");
    __builtin_amdgcn_sched_barrier(0);
    __builtin_amdgcn_s_setprio(1);
    #pragma unroll
    for (int mi = 0; mi < 4; ++mi)
        #pragma unroll
        for (int ni = 0; ni < 4; ++ni)
            acc[MH * 4 + mi][ni] = __builtin_amdgcn_mfma_f32_16x16x32_bf16(
                af[mi], bfr[ni], acc[MH * 4 + mi][ni], 0, 0, 0);
    __builtin_amdgcn_s_setprio(0);
    if (DOVM) asm volatile("s_waitcnt vmcnt(8)" ::: "memory");
    __builtin_amdgcn_sched_barrier(0);
    __builtin_amdgcn_s_barrier();
    __builtin_amdgcn_sched_barrier(0);
}

// KROW: row stride of A and Bt; KLEN: K extent per wg (split-K slice); NCOLT: output
// 256-col tiles; SPLITK: slices (partial slabs of 4096*LDC fp32 each, concatenated);
// OUTMODE 0: C fp32.  2: Cb bf16.  3: Cb = h bf16 (ld 4096) + C = energy fp32 (ld 512).
template<int KROW, int KLEN, int NCOLT, int SPLITK, int LDC, int OUTMODE>
__global__ __launch_bounds__(512, 1) void k_gemm8(const unsigned short* __restrict__ A,
                                                  const unsigned short* __restrict__ Bt,
                                                  float* __restrict__ C,
                                                  unsigned short* __restrict__ Cb)
{
    __shared__ unsigned short lds[2][2][2][8192];   // 128 KiB

    constexpr int KT   = KLEN / 64;
    constexpr int NIT  = KLEN / 128;
    constexpr int ROWT = 16;                        // 4096 / 256
    constexpr int NWG  = ROWT * NCOLT * SPLITK;     // must be % 8 == 0

    int tid = threadIdx.x;
    int wid = tid >> 6;
    int lane = tid & 63;
    int wr = wid >> 2, wc = wid & 3;

    int bid = blockIdx.x;
    int swz = (bid & 7) * (NWG / 8) + (bid >> 3);
    int ks   = swz / (ROWT * NCOLT);
    int tile = swz % (ROWT * NCOLT);
    int brow = (tile / NCOLT) * 256;
    int bcol = (tile % NCOLT) * 256;

    const unsigned short* Aofs = A + (size_t)ks * KLEN;
    const unsigned short* Bofs = Bt + (size_t)ks * KLEN;
    float* Cofs = C + (size_t)ks * 4096 * LDC;

    f32x4 acc[8][4] = {};
    short8 bfr[4];

    // ---- prologue: stage tile0 (4 units) + tile1.kc0 (2 units) ----
    auto stage0 = [&](int sbuf, int sop, int skc, int stile) {
        const unsigned short* src = sop ? Bofs : Aofs;
        int rbase = sop ? bcol : brow;
        #pragma unroll
        for (int j = 0; j < 2; ++j) {
            int c = wid * 128 + j * 64 + lane;
            int row = c >> 2, k8 = c & 3;
            int k8s = k8 ^ (row & 3);
            const unsigned short* gp = src + (size_t)(rbase + row) * KROW
                                     + stile * 64 + skc * 32 + k8s * 8;
            unsigned short* lp = lds[sbuf][sop][skc] + (wid * 128 + j * 64) * 8;
            gload_lds16(gp, lp);
        }
    };
    stage0(0, 0, 0, 0); stage0(0, 1, 0, 0);
    stage0(0, 0, 1, 0); stage0(0, 1, 1, 0);
    stage0(1, 0, 0, 1); stage0(1, 1, 0, 1);
    asm volatile("s_waitcnt vmcnt(8)" ::: "memory");
    __builtin_amdgcn_sched_barrier(0);
    __builtin_amdgcn_s_barrier();
    __builtin_amdgcn_sched_barrier(0);

    for (int i = 0; i < NIT; ++i) {
        int t1 = 2 * i + 1; if (t1 > KT - 1) t1 = KT - 1;
        int t2 = 2 * i + 2; if (t2 > KT - 1) t2 = KT - 1;
        int t3 = 2 * i + 3; if (t3 > KT - 1) t3 = KT - 1;
        gemm_phase<KROW, 0, 0, 0, true , 1, 0, 1, false>(Aofs, Bofs, lds, acc, bfr, wr, wc, lane, wid, brow, bcol, t1);
        gemm_phase<KROW, 0, 0, 1, false, 1, 1, 1, true >(Aofs, Bofs, lds, acc, bfr, wr, wc, lane, wid, brow, bcol, t1);
        gemm_phase<KROW, 0, 1, 0, true , 0, 0, 0, false>(Aofs, Bofs, lds, acc, bfr, wr, wc, lane, wid, brow, bcol, t2);
        gemm_phase<KROW, 0, 1, 1, false, 0, 1, 0, true >(Aofs, Bofs, lds, acc, bfr, wr, wc, lane, wid, brow, bcol, t2);
        gemm_phase<KROW, 1, 0, 0, true , 0, 0, 1, false>(Aofs, Bofs, lds, acc, bfr, wr, wc, lane, wid, brow, bcol, t2);
        gemm_phase<KROW, 1, 0, 1, false, 0, 1, 1, true >(Aofs, Bofs, lds, acc, bfr, wr, wc, lane, wid, brow, bcol, t2);
        gemm_phase<KROW, 1, 1, 0, true , 1, 0, 0, false>(Aofs, Bofs, lds, acc, bfr, wr, wc, lane, wid, brow, bcol, t3);
        gemm_phase<KROW, 1, 1, 1, false, 1, 1, 0, true >(Aofs, Bofs, lds, acc, bfr, wr, wc, lane, wid, brow, bcol, t3);
    }

    // epilogue: C/D layout col=lane&15, row=(lane>>4)*4+reg  [verified m89/m91]
    if (OUTMODE != 3) {
        #pragma unroll
        for (int mr = 0; mr < 8; ++mr) {
            int row0 = brow + wr * 128 + mr * 16 + (lane >> 4) * 4;
            #pragma unroll
            for (int nr = 0; nr < 4; ++nr) {
                int col = bcol + wc * 64 + nr * 16 + (lane & 15);
                #pragma unroll
                for (int r = 0; r < 4; ++r) {
                    if (OUTMODE == 0)
                        Cofs[(size_t)(row0 + r) * LDC + col] = acc[mr][nr][r];
                    else
                        Cb[(size_t)(row0 + r) * LDC + col] = f2b(acc[mr][nr][r]);
                }
            }
        }
    } else {
        #pragma unroll
        for (int mr = 0; mr < 8; ++mr) {
            int row0 = brow + wr * 128 + mr * 16 + (lane >> 4) * 4;
            #pragma unroll
            for (int nr = 0; nr < 4; ++nr) {
                int col = bcol + wc * 64 + nr * 16 + (lane & 15);
                f32x4 a = acc[mr][nr];
                #pragma unroll
                for (int r = 0; r < 4; ++r)
                    Cb[(size_t)(row0 + r) * 4096 + col] = f2b(a[r]);
                // energy: sum h^2 over the 8-lane b-group (3x shfl_xor tree)
                f32x4 sq;
                #pragma unroll
                for (int r = 0; r < 4; ++r) sq[r] = a[r] * a[r];
                #pragma unroll
                for (int off = 1; off <= 4; off <<= 1) {
                    sq[0] += __shfl_xor(sq[0], off);
                    sq[1] += __shfl_xor(sq[1], off);
                    sq[2] += __shfl_xor(sq[2], off);
                    sq[3] += __shfl_xor(sq[3], off);
                }
                if ((lane & 7) == 0) {
                    int e = ((bcol + wc * 64 + nr * 16) >> 3) + ((lane >> 3) & 1);
                    #pragma unroll
                    for (int r = 0; r < 4; ++r)
                        C[(size_t)(row0 + r) * 512 + e] = sq[r];
                }
            }
        }
    }
}

// ---- top-16 from energy; mask hbf in place; gather h_sel (one wave per token) ----
__global__ __launch_bounds__(256) void k_topk2(const float* __restrict__ energy,
                                               unsigned short* __restrict__ hbf,
                                               int* __restrict__ topk_idx,
                                               int* __restrict__ counts,
                                               float* __restrict__ h_sel)
{
    int wave = threadIdx.x >> 6;
    int lane = threadIdx.x & 63;
    int n = blockIdx.x * 4 + wave;
    float ev[8];
    #pragma unroll
    for (int i = 0; i < 8; ++i) ev[i] = energy[(size_t)n * M_EXP + i * 64 + lane];
    for (int r = 0; r < K_TOP; ++r) {
        float bv = -1.0f; int bi = 0;
        #pragma unroll
        for (int i = 0; i < 8; ++i) {
            if (ev[i] > bv) { bv = ev[i]; bi = i * 64 + lane; }
        }
        #pragma unroll
        for (int off = 1; off < 64; off <<= 1) {
            float ov = __shfl_xor(bv, off);
            int   oi = __shfl_xor(bi, off);
            if (ov > bv || (ov == bv && oi < bi)) { bv = ov; bi = oi; }
        }
        if (lane == 0) {
            topk_idx[n * K_TOP + r] = bi;
            atomicAdd(&counts[bi], 1);
        }
        if (lane < 8)
            h_sel[(size_t)n * 128 + r * 8 + lane] =
                b2f(hbf[(size_t)n * MB + bi * 8 + lane]);
        #pragma unroll
        for (int i = 0; i < 8; ++i)
            if (((bi >> 6) == i) && (lane == (bi & 63))) ev[i] = -INFINITY;
    }
    // zero non-selected experts' h (selected entries already hold h from GEMM1)
    ushort8 z = {0, 0, 0, 0, 0, 0, 0, 0};
    #pragma unroll
    for (int i = 0; i < 8; ++i) {
        int e = i * 64 + lane;
        if (ev[i] != -INFINITY)
            *(ushort8*)&hbf[(size_t)n * MB + e * 8] = z;
    }
}

// ---- fused: reduce 4 split-K partials + x_out + uncap + writesb (one token/block) ----
__global__ __launch_bounds__(256) void k_reduce_fin(const float* __restrict__ P,
                                                    const float* __restrict__ xn,
                                                    float* __restrict__ x_out,
                                                    unsigned short* __restrict__ wb,
                                                    float* __restrict__ uncap)
{
    const size_t S = (size_t)4096 * 1024;
    int n = blockIdx.x;
    int t = threadIdx.x;
    int c = t * 4;                               // 0..1023, step 4
    size_t base = (size_t)n * 1024 + c;
    float4 a = *(const float4*)&P[base];
    float4 b = *(const float4*)&P[base + S];
    float4 cc = *(const float4*)&P[base + 2 * S];
    float4 d = *(const float4*)&P[base + 3 * S];
    float4 v = make_float4(a.x + b.x + cc.x + d.x, a.y + b.y + cc.y + d.y,
                           a.z + b.z + cc.z + d.z, a.w + b.w + cc.w + d.w);
    bool isW = (c < 512);
    int xc = isW ? c : (c - 512);
    float4 xv = *(const float4*)&xn[(size_t)n * D_DIM + xc];
    float4 yr;                                    // y (writes half) or resid (xhat half)
    if (isW) yr = make_float4(xv.x + v.x, xv.y + v.y, xv.z + v.z, xv.w + v.w);
    else     yr = make_float4(xv.x - v.x, xv.y - v.y, xv.z - v.z, xv.w - v.w);
    float local = yr.x*yr.x + yr.y*yr.y + yr.z*yr.z + yr.w*yr.w;

    __shared__ float red[256];
    __shared__ float sinv;
    red[t] = local;
    __syncthreads();
    for (int s = 64; s > 0; s >>= 1) {
        if ((t & 127) < s) red[t] += red[t + s];
        __syncthreads();
    }
    if (t == 0) {
        uncap[n] = red[128];                      // sum resid^2
        sinv = 1.0f / fmaxf(sqrtf(red[0]), EPSV); // from sum y^2
    }
    __syncthreads();
    if (isW) {
        float inv = sinv;
        *(float4*)&x_out[(size_t)n * D_DIM + c] =
            make_float4(yr.x*inv, yr.y*inv, yr.z*inv, yr.w*inv);
        ushort4v o;
        o[0] = f2b(yr.x); o[1] = f2b(yr.y); o[2] = f2b(yr.z); o[3] = f2b(yr.w);
        *(ushort4v*)&wb[(size_t)n * 512 + c] = o;
    }
}

// ---------- writer loss only (one wave per token) ----------
__global__ __launch_bounds__(256) void k_fin_writer(const unsigned short* __restrict__ hrecon,
                                                    const float* __restrict__ h_sel,
                                                    const int* __restrict__ topk_idx,
                                                    float* __restrict__ writer)
{
    int wave = threadIdx.x >> 6;
    int lane = threadIdx.x & 63;
    int n = blockIdx.x * 4 + wave;
    float acc = 0.f;
    #pragma unroll
    for (int pp = 0; pp < 2; ++pp) {
        int p = lane + pp * 64;
        int m = topk_idx[n * K_TOP + (p >> 3)];
        float d = b2f(hrecon[(size_t)n * MB + m * 8 + (p & 7)])
                - h_sel[(size_t)n * 128 + p];
        acc += d * d;
    }
    #pragma unroll
    for (int off = 1; off < 64; off <<= 1) acc += __shfl_xor(acc, off);
    if (lane == 0) writer[n] = acc;
}

// ---------------- final scalar reductions + counts ----------------
__global__ __launch_bounds__(256) void k_finalize(const float* __restrict__ uncap,
                                                  const float* __restrict__ writer,
                                                  const int* __restrict__ counts,
                                                  float* __restrict__ out)
{
    __shared__ float ru[256], rw[256];
    int t = threadIdx.x;
    float su = 0.f, sw = 0.f;
    for (int i = t; i < N_TOK; i += 256) { su += uncap[i]; sw += writer[i]; }
    ru[t] = su; rw[t] = sw;
    __syncthreads();
    for (int s = 128; s > 0; s >>= 1) {
        if (t < s) { ru[t] += ru[t + s]; rw[t] += rw[t + s]; }
        __syncthreads();
    }
    if (t == 0)
        out[(size_t)N_TOK * D_DIM] = ru[0] / (float)N_TOK
                                   + rw[0] / (float)(N_TOK * K_TOP * B_DIM);
    for (int i = t; i < M_EXP; i += 256)
        out[(size_t)N_TOK * D_DIM + 1 + i] = (float)counts[i];
}

extern "C" void kernel_launch(void* const* d_in, const int* in_sizes, int n_in,
                              void* d_out, int out_size, void* d_ws, size_t ws_size,
                              hipStream_t stream)
{
    const float* x = (const float*)d_in[0];
    const float* V = (const float*)d_in[1];
    const float* U = (const float*)d_in[2];
    float* out = (float*)d_out;

    float* ws     = (float*)d_ws;
    float* xn     = ws;                        // 2,097,152 f  (8.4 MB)
    float* P      = xn + 2097152;              // 16,777,216 f (67.1 MB): GEMM1 energy,
                                               //   then GEMM23 partials, then hrecon
    float* uncap  = P + 16777216;              // 4096 f
    float* writer = uncap + 4096;              // 4096 f
    int*   topk_i = (int*)(writer + 4096);     // 65,536 i
    int*   counts = topk_i + 65536;            // 512 i (+pad)
    float* partV  = (float*)(counts + 1024);   // 65,536 f
    float* partU  = partV + 65536;             // 65,536 f
    float* h_sel  = partU + 65536;             // 524,288 f (2.1 MB)
    unsigned short* hbf = (unsigned short*)(h_sel + 524288); // 16,777,216 us (33.6 MB)
    unsigned short* U2t = hbf + 16777216;      // 2,097,152 us (4.2 MB)
    unsigned short* WXt = U2t + 2097152;       // 4,194,304 us (8.4 MB)
    unsigned short* R   = WXt + 4194304;       // 12,582,912 us (25.2 MB)
    unsigned short* Abf  = R;                  // 6,291,456 us (gemm1 A')
    unsigned short* Btbf = R + 6291456;        // 6,291,456 us (gemm1 B')
    unsigned short* writesb = R;               // 2,097,152 us (aliases Abf after GEMM1)
    float* energy = P;                         // 2,097,152 f ⊂ P
    unsigned short* hrecon = (unsigned short*)P; // 16,777,216 us ⊂ P (after reduce_fin)
    // total ws use ~150 MB

    hipMemsetAsync(counts, 0, M_EXP * sizeof(int), stream);
    k_norm_x    <<<N_TOK / 4, 256, 0, stream>>>(x, xn, Abf);
    k_vnorm_part<<<256, 256, 0, stream>>>(V, partV);
    k_norm_V2   <<<256, 256, 0, stream>>>(V, partV, Btbf, WXt);
    k_unorm_part<<<256, 256, 0, stream>>>(U, partU);
    k_norm_U2   <<<256, 256, 0, stream>>>(U, partU, WXt, U2t);
    // GEMM1: h = A'(4096x1536) @ B'(1536x4096) -> hbf bf16 + energy fp32 (epilogue-fused)
    k_gemm8<KTOT, KTOT, 16, 1, 4096, 3><<<256, 512, 0, stream>>>(Abf, Btbf, energy, hbf);
    k_topk2     <<<N_TOK / 4, 256, 0, stream>>>(energy, hbf, topk_i, counts, h_sel);
    // GEMM23: partial[ks] = hbf(4096x4096, K-slice ks) @ WXt^T -> 4x(4096x1024) in P
    k_gemm8<4096, 1024, 4, 4, 1024, 0><<<256, 512, 0, stream>>>(hbf, WXt, P, nullptr);
    // fused reduce + x_out + uncap + writes bf16
    k_reduce_fin<<<4096, 256, 0, stream>>>(P, xn, out, writesb, uncap);
    // GEMM4: hrecon = writesb(4096x512) @ U2t^T -> (4096x4096) bf16 (into P)
    k_gemm8<D_DIM, D_DIM, 16, 1, 4096, 2><<<256, 512, 0, stream>>>(writesb, U2t, nullptr, hrecon);
    k_fin_writer<<<N_TOK / 4, 256, 0, stream>>>(hrecon, h_sel, topk_i, writer);
    k_finalize  <<<1, 256, 0, stream>>>(uncap, writer, counts, out);
}

// Round 9
// 212.598 us; speedup vs baseline: 3.1574x; 1.0983x over previous
//
#include <hip/hip_runtime.h>
#include <math.h>

#define N_TOK 4096
#define D_DIM 512
#define M_EXP 512
#define B_DIM 8
#define K_TOP 16
#define MB    4096          // M_EXP * B_DIM
#define UROW  4104          // (D_DIM+1) * B_DIM
#define EPSV  1e-8f
#define KTOT  1536          // 3 * D (split-bf16 K blocks for GEMM1)

typedef unsigned short ushort8 __attribute__((ext_vector_type(8)));
typedef unsigned short ushort4v __attribute__((ext_vector_type(4)));
typedef short short8 __attribute__((ext_vector_type(8)));
typedef float f32x4 __attribute__((ext_vector_type(4)));

__device__ inline float b2f(unsigned short u) {
    union { unsigned int i; float f; } c;
    c.i = ((unsigned int)u) << 16;
    return c.f;
}
__device__ inline unsigned short f2b(float f) {     // RNE bf16
    union { float f; unsigned int i; } c; c.f = f;
    unsigned int lsb = (c.i >> 16) & 1;
    c.i += 0x7fffu + lsb;
    return (unsigned short)(c.i >> 16);
}
__device__ inline void gload_lds16(const unsigned short* g, unsigned short* l) {
    __builtin_amdgcn_global_load_lds(
        (const __attribute__((address_space(1))) unsigned int*)g,
        (__attribute__((address_space(3))) unsigned int*)l, 16, 0, 0);
}

// --- normalize x rows; emit xn fp32 + A' = [hi|hi|lo] bf16; block 0 zeroes counts ---
__global__ __launch_bounds__(256) void k_norm_x(const float* __restrict__ x,
                                                float* __restrict__ xn,
                                                unsigned short* __restrict__ Abf,
                                                int* __restrict__ counts)
{
    if (blockIdx.x == 0) {
        counts[threadIdx.x] = 0;
        counts[threadIdx.x + 256] = 0;
    }
    int wave = threadIdx.x >> 6;
    int lane = threadIdx.x & 63;
    int n = blockIdx.x * 4 + wave;
    const float4* xp = (const float4*)&x[(size_t)n * D_DIM + lane * 8];
    float4 a = xp[0], b = xp[1];
    float s = a.x*a.x + a.y*a.y + a.z*a.z + a.w*a.w
            + b.x*b.x + b.y*b.y + b.z*b.z + b.w*b.w;
    #pragma unroll
    for (int off = 1; off < 64; off <<= 1) s += __shfl_xor(s, off);
    float inv = 1.0f / fmaxf(sqrtf(s), EPSV);
    float v[8] = {a.x*inv, a.y*inv, a.z*inv, a.w*inv,
                  b.x*inv, b.y*inv, b.z*inv, b.w*inv};
    float4* op = (float4*)&xn[(size_t)n * D_DIM + lane * 8];
    op[0] = make_float4(v[0], v[1], v[2], v[3]);
    op[1] = make_float4(v[4], v[5], v[6], v[7]);
    ushort8 hi, lo;
    #pragma unroll
    for (int j = 0; j < 8; ++j) {
        unsigned short h = f2b(v[j]);
        hi[j] = h;
        lo[j] = f2b(v[j] - b2f(h));
    }
    size_t base = (size_t)n * KTOT + lane * 8;
    *(ushort8*)&Abf[base]        = hi;
    *(ushort8*)&Abf[base + 512]  = hi;
    *(ushort8*)&Abf[base + 1024] = lo;
}

// ---- merged V/U column-norm partials: blocks 0-255 -> V, 256-511 -> U ----
__global__ __launch_bounds__(256) void k_uvnorm_part(const float* __restrict__ V,
                                                     const float* __restrict__ U,
                                                     float* __restrict__ partV,
                                                     float* __restrict__ partU)
{
    int blk = blockIdx.x;
    if (blk < 256) {
        int s = blk >> 4;
        int t = (blk & 15) * 256 + threadIdx.x;
        float sum = 0.f;
        int d0 = s * 32;
        #pragma unroll 8
        for (int d = d0; d < d0 + 32; ++d) {
            float v = V[(size_t)d * MB + t];
            sum += v * v;
        }
        partV[(size_t)s * MB + t] = sum;
    } else {
        blk -= 256;
        int s = blk >> 4;
        int t = (blk & 15) * 256 + threadIdx.x;
        int m = t >> 3, b = t & 7;
        size_t base = (size_t)m * UROW + b;
        int pbeg = s * 32;
        int pend = (s == 15) ? 513 : pbeg + 32;
        float sum = 0.f;
        for (int p = pbeg; p < pend; ++p) {
            float u = U[base + (size_t)p * 8];
            sum += u * u;
        }
        partU[(size_t)s * MB + t] = sum;
    }
}

// ---- merged normalize+emit: blocks 0-255 -> V path, 256-511 -> U path ----
__global__ __launch_bounds__(256) void k_norm_UV2(const float* __restrict__ V,
                                                  const float* __restrict__ U,
                                                  const float* __restrict__ partV,
                                                  const float* __restrict__ partU,
                                                  unsigned short* __restrict__ Btbf,
                                                  unsigned short* __restrict__ WXt,
                                                  unsigned short* __restrict__ U2t)
{
    int blk = blockIdx.x;
    if (blk < 256) {
        int s = blk >> 4;
        int t = (blk & 15) * 256 + threadIdx.x;
        float n2 = 0.f;
        #pragma unroll
        for (int i = 0; i < 16; ++i) n2 += partV[(size_t)i * MB + t];
        float inv = 1.0f / fmaxf(sqrtf(n2), EPSV);
        size_t row = (size_t)t * KTOT;
        int dbeg = s * 32;
        for (int d0 = dbeg; d0 < dbeg + 32; d0 += 8) {
            ushort8 hi, lo;
            #pragma unroll
            for (int j = 0; j < 8; ++j) {
                float f = V[(size_t)(d0 + j) * MB + t] * inv;
                unsigned short h = f2b(f);
                hi[j] = h;
                lo[j] = f2b(f - b2f(h));
                WXt[(size_t)(512 + d0 + j) * MB + t] = h;
            }
            *(ushort8*)&Btbf[row + d0]        = hi;
            *(ushort8*)&Btbf[row + 512 + d0]  = lo;
            *(ushort8*)&Btbf[row + 1024 + d0] = hi;
        }
    } else {
        blk -= 256;
        int s = blk >> 4;
        int t = (blk & 15) * 256 + threadIdx.x;
        int m = t >> 3, b = t & 7;
        size_t base = (size_t)m * UROW + b;
        float n2 = 0.f;
        #pragma unroll
        for (int i = 0; i < 16; ++i) n2 += partU[(size_t)i * MB + t];
        float inv = 1.0f / fmaxf(sqrtf(n2), EPSV);
        int pbeg = s * 32;
        for (int p0 = pbeg; p0 < pbeg + 32; p0 += 8) {
            ushort8 h8;
            #pragma unroll
            for (int j = 0; j < 8; ++j) {
                unsigned short h = f2b(U[base + (size_t)(p0 + j) * 8] * inv);
                h8[j] = h;
                WXt[(size_t)(p0 + j) * MB + t] = h;
            }
            *(ushort8*)&U2t[(size_t)t * D_DIM + p0] = h8;
        }
    }
}

// ================== 8-phase 256x256 bf16 GEMM (T3+T4+T5, k-slot swizzle) ==================
// A row-major (4096 x KROW), Bt col-major (Bt[col*KROW + k]).
// LDS: lds[buf][op][kc][row*32 + k], unit (buf,op,kc) = 16KB staged by 2 gload_lds16/thread.
// k-slot swizzle f(r) = (r>>1)&3: physical slot p of row r holds global slot p ^ f(r).
// (8 consecutive lanes then hit 8 distinct bank-quads -> conflict-free ds_read_b128.)
template<int KROW, int BUF, int KC, int MH, bool READB, int SBUF, int SOP, int SKC, bool DOVM>
__device__ __forceinline__ void gemm_phase(const unsigned short* __restrict__ A,
                                           const unsigned short* __restrict__ Bt,
                                           unsigned short (*lds)[2][2][8192],
                                           f32x4 (&acc)[8][4], short8 (&bfr)[4],
                                           int wr, int wc, int lane, int wid,
                                           int brow, int bcol, int stile)
{
    const unsigned short* aun = lds[BUF][0][KC];
    const unsigned short* bun = lds[BUF][1][KC];
    int ko = ((lane >> 4) ^ ((lane >> 1) & 3)) * 8;   // swizzled k-slot for this lane
    short8 af[4];
    #pragma unroll
    for (int mi = 0; mi < 4; ++mi) {
        int rowL = wr * 128 + (MH * 4 + mi) * 16 + (lane & 15);
        af[mi] = *(const short8*)&aun[rowL * 32 + ko];
    }
    if (READB) {
        #pragma unroll
        for (int ni = 0; ni < 4; ++ni) {
            int colL = wc * 64 + ni * 16 + (lane & 15);
            bfr[ni] = *(const short8*)&bun[colL * 32 + ko];
        }
    }
    // stage one unit (pre-swizzled global source, linear LDS dest)
    {
        const unsigned short* src = SOP ? Bt : A;
        int rbase = SOP ? bcol : brow;
        #pragma unroll
        for (int j = 0; j < 2; ++j) {
            int c = wid * 128 + j * 64 + lane;
            int row = c >> 2, k8 = c & 3;
            int k8s = k8 ^ ((row >> 1) & 3);
            const unsigned short* gp = src + (size_t)(rbase + row) * KROW
                                     + stile * 64 + SKC * 32 + k8s * 8;
            unsigned short* lp = lds[SBUF][SOP][SKC] + (wid * 128 + j * 64) * 8;
            gload_lds16(gp, lp);
        }
    }
    __builtin_amdgcn_sched_barrier(0);
    __builtin_amdgcn_s_barrier();
    asm volatile("s_waitcnt lgkmcnt(0)" ::: "memory");
    __builtin_amdgcn_sched_barrier(0);
    __builtin_amdgcn_s_setprio(1);
    #pragma unroll
    for (int mi = 0; mi < 4; ++mi)
        #pragma unroll
        for (int ni = 0; ni < 4; ++ni)
            acc[MH * 4 + mi][ni] = __builtin_amdgcn_mfma_f32_16x16x32_bf16(
                af[mi], bfr[ni], acc[MH * 4 + mi][ni], 0, 0, 0);
    __builtin_amdgcn_s_setprio(0);
    if (DOVM) asm volatile("s_waitcnt vmcnt(8)" ::: "memory");
    __builtin_amdgcn_sched_barrier(0);
    __builtin_amdgcn_s_barrier();
    __builtin_amdgcn_sched_barrier(0);
}

// KROW: row stride of A and Bt; KLEN: K extent per wg (split-K slice); NCOLT: output
// 256-col tiles; SPLITK: slices (partial slabs of 4096*LDC fp32 each, concatenated).
// OUTMODE 0: C fp32.  2: Cb bf16.  3: Cb = h bf16 (ld 4096) + C = energy fp32 (ld 512).
// OUTMODE 4: writer-loss fused: Cb = hbf INPUT (masked h, ld 4096); C[bid] = block partial.
template<int KROW, int KLEN, int NCOLT, int SPLITK, int LDC, int OUTMODE>
__global__ __launch_bounds__(512, 1) void k_gemm8(const unsigned short* __restrict__ A,
                                                  const unsigned short* __restrict__ Bt,
                                                  float* __restrict__ C,
                                                  unsigned short* __restrict__ Cb)
{
    __shared__ unsigned short lds[2][2][2][8192];   // 128 KiB

    constexpr int KT   = KLEN / 64;
    constexpr int NIT  = KLEN / 128;
    constexpr int ROWT = 16;                        // 4096 / 256
    constexpr int NWG  = ROWT * NCOLT * SPLITK;     // must be % 8 == 0

    int tid = threadIdx.x;
    int wid = tid >> 6;
    int lane = tid & 63;
    int wr = wid >> 2, wc = wid & 3;

    int bid = blockIdx.x;
    int swz = (bid & 7) * (NWG / 8) + (bid >> 3);
    int ks   = swz / (ROWT * NCOLT);
    int tile = swz % (ROWT * NCOLT);
    int brow = (tile / NCOLT) * 256;
    int bcol = (tile % NCOLT) * 256;

    const unsigned short* Aofs = A + (size_t)ks * KLEN;
    const unsigned short* Bofs = Bt + (size_t)ks * KLEN;
    float* Cofs = C + (size_t)ks * 4096 * LDC;

    f32x4 acc[8][4] = {};
    short8 bfr[4];

    // ---- prologue: stage tile0 (4 units) + tile1.kc0 (2 units) ----
    auto stage0 = [&](int sbuf, int sop, int skc, int stile) {
        const unsigned short* src = sop ? Bofs : Aofs;
        int rbase = sop ? bcol : brow;
        #pragma unroll
        for (int j = 0; j < 2; ++j) {
            int c = wid * 128 + j * 64 + lane;
            int row = c >> 2, k8 = c & 3;
            int k8s = k8 ^ ((row >> 1) & 3);
            const unsigned short* gp = src + (size_t)(rbase + row) * KROW
                                     + stile * 64 + skc * 32 + k8s * 8;
            unsigned short* lp = lds[sbuf][sop][skc] + (wid * 128 + j * 64) * 8;
            gload_lds16(gp, lp);
        }
    };
    stage0(0, 0, 0, 0); stage0(0, 1, 0, 0);
    stage0(0, 0, 1, 0); stage0(0, 1, 1, 0);
    stage0(1, 0, 0, 1); stage0(1, 1, 0, 1);
    asm volatile("s_waitcnt vmcnt(8)" ::: "memory");
    __builtin_amdgcn_sched_barrier(0);
    __builtin_amdgcn_s_barrier();
    __builtin_amdgcn_sched_barrier(0);

    for (int i = 0; i < NIT; ++i) {
        int t1 = 2 * i + 1; if (t1 > KT - 1) t1 = KT - 1;
        int t2 = 2 * i + 2; if (t2 > KT - 1) t2 = KT - 1;
        int t3 = 2 * i + 3; if (t3 > KT - 1) t3 = KT - 1;
        gemm_phase<KROW, 0, 0, 0, true , 1, 0, 1, false>(Aofs, Bofs, lds, acc, bfr, wr, wc, lane, wid, brow, bcol, t1);
        gemm_phase<KROW, 0, 0, 1, false, 1, 1, 1, true >(Aofs, Bofs, lds, acc, bfr, wr, wc, lane, wid, brow, bcol, t1);
        gemm_phase<KROW, 0, 1, 0, true , 0, 0, 0, false>(Aofs, Bofs, lds, acc, bfr, wr, wc, lane, wid, brow, bcol, t2);
        gemm_phase<KROW, 0, 1, 1, false, 0, 1, 0, true >(Aofs, Bofs, lds, acc, bfr, wr, wc, lane, wid, brow, bcol, t2);
        gemm_phase<KROW, 1, 0, 0, true , 0, 0, 1, false>(Aofs, Bofs, lds, acc, bfr, wr, wc, lane, wid, brow, bcol, t2);
        gemm_phase<KROW, 1, 0, 1, false, 0, 1, 1, true >(Aofs, Bofs, lds, acc, bfr, wr, wc, lane, wid, brow, bcol, t2);
        gemm_phase<KROW, 1, 1, 0, true , 1, 0, 0, false>(Aofs, Bofs, lds, acc, bfr, wr, wc, lane, wid, brow, bcol, t3);
        gemm_phase<KROW, 1, 1, 1, false, 1, 1, 0, true >(Aofs, Bofs, lds, acc, bfr, wr, wc, lane, wid, brow, bcol, t3);
    }

    // epilogue: C/D layout col=lane&15, row=(lane>>4)*4+reg  [verified m89/m91]
    if (OUTMODE == 0 || OUTMODE == 2) {
        #pragma unroll
        for (int mr = 0; mr < 8; ++mr) {
            int row0 = brow + wr * 128 + mr * 16 + (lane >> 4) * 4;
            #pragma unroll
            for (int nr = 0; nr < 4; ++nr) {
                int col = bcol + wc * 64 + nr * 16 + (lane & 15);
                #pragma unroll
                for (int r = 0; r < 4; ++r) {
                    if (OUTMODE == 0)
                        Cofs[(size_t)(row0 + r) * LDC + col] = acc[mr][nr][r];
                    else
                        Cb[(size_t)(row0 + r) * LDC + col] = f2b(acc[mr][nr][r]);
                }
            }
        }
    } else if (OUTMODE == 3) {
        #pragma unroll
        for (int mr = 0; mr < 8; ++mr) {
            int row0 = brow + wr * 128 + mr * 16 + (lane >> 4) * 4;
            #pragma unroll
            for (int nr = 0; nr < 4; ++nr) {
                int col = bcol + wc * 64 + nr * 16 + (lane & 15);
                f32x4 a = acc[mr][nr];
                #pragma unroll
                for (int r = 0; r < 4; ++r)
                    Cb[(size_t)(row0 + r) * 4096 + col] = f2b(a[r]);
                // energy: sum h^2 over the 8-lane b-group (3x shfl_xor tree)
                f32x4 sq;
                #pragma unroll
                for (int r = 0; r < 4; ++r) sq[r] = a[r] * a[r];
                #pragma unroll
                for (int off = 1; off <= 4; off <<= 1) {
                    sq[0] += __shfl_xor(sq[0], off);
                    sq[1] += __shfl_xor(sq[1], off);
                    sq[2] += __shfl_xor(sq[2], off);
                    sq[3] += __shfl_xor(sq[3], off);
                }
                if ((lane & 7) == 0) {
                    int e = ((bcol + wc * 64 + nr * 16) >> 3) + ((lane >> 3) & 1);
                    #pragma unroll
                    for (int r = 0; r < 4; ++r)
                        C[(size_t)(row0 + r) * 512 + e] = sq[r];
                }
            }
        }
    } else {  // OUTMODE 4: writer loss partial, no hrecon materialization
        float local = 0.f;
        #pragma unroll
        for (int mr = 0; mr < 8; ++mr) {
            int row0 = brow + wr * 128 + mr * 16 + (lane >> 4) * 4;
            #pragma unroll
            for (int nr = 0; nr < 4; ++nr) {
                int col = bcol + wc * 64 + nr * 16 + (lane & 15);
                #pragma unroll
                for (int r = 0; r < 4; ++r) {
                    unsigned short hbits = Cb[(size_t)(row0 + r) * 4096 + col];
                    if (hbits & 0x7fffu) {
                        float d = acc[mr][nr][r] - b2f(hbits);
                        local += d * d;
                    }
                }
            }
        }
        __syncthreads();                 // LDS dead after K-loop; reuse for reduction
        float* red = (float*)lds;
        red[tid] = local;
        __syncthreads();
        for (int s = 256; s > 0; s >>= 1) {
            if (tid < s) red[tid] += red[tid + s];
            __syncthreads();
        }
        if (tid == 0) C[bid] = red[0];
    }
}

// ---- top-16 from energy; mask hbf in place (one wave per token) ----
__global__ __launch_bounds__(256) void k_topk2(const float* __restrict__ energy,
                                               unsigned short* __restrict__ hbf,
                                               int* __restrict__ topk_idx,
                                               int* __restrict__ counts)
{
    int wave = threadIdx.x >> 6;
    int lane = threadIdx.x & 63;
    int n = blockIdx.x * 4 + wave;
    float ev[8];
    #pragma unroll
    for (int i = 0; i < 8; ++i) ev[i] = energy[(size_t)n * M_EXP + i * 64 + lane];
    for (int r = 0; r < K_TOP; ++r) {
        float bv = -1.0f; int bi = 0;
        #pragma unroll
        for (int i = 0; i < 8; ++i) {
            if (ev[i] > bv) { bv = ev[i]; bi = i * 64 + lane; }
        }
        #pragma unroll
        for (int off = 1; off < 64; off <<= 1) {
            float ov = __shfl_xor(bv, off);
            int   oi = __shfl_xor(bi, off);
            if (ov > bv || (ov == bv && oi < bi)) { bv = ov; bi = oi; }
        }
        if (lane == 0) {
            topk_idx[n * K_TOP + r] = bi;
            atomicAdd(&counts[bi], 1);
        }
        #pragma unroll
        for (int i = 0; i < 8; ++i)
            if (((bi >> 6) == i) && (lane == (bi & 63))) ev[i] = -INFINITY;
    }
    // zero non-selected experts' h (selected entries already hold h from GEMM1)
    ushort8 z = {0, 0, 0, 0, 0, 0, 0, 0};
    #pragma unroll
    for (int i = 0; i < 8; ++i) {
        int e = i * 64 + lane;
        if (ev[i] != -INFINITY)
            *(ushort8*)&hbf[(size_t)n * MB + e * 8] = z;
    }
}

// ---- fused: reduce 4 split-K partials + x_out + uncap + writesb (one token/block) ----
__global__ __launch_bounds__(256) void k_reduce_fin(const float* __restrict__ P,
                                                    const float* __restrict__ xn,
                                                    float* __restrict__ x_out,
                                                    unsigned short* __restrict__ wb,
                                                    float* __restrict__ uncap)
{
    const size_t S = (size_t)4096 * 1024;
    int n = blockIdx.x;
    int t = threadIdx.x;
    int c = t * 4;                               // 0..1023, step 4
    size_t base = (size_t)n * 1024 + c;
    float4 a = *(const float4*)&P[base];
    float4 b = *(const float4*)&P[base + S];
    float4 cc = *(const float4*)&P[base + 2 * S];
    float4 d = *(const float4*)&P[base + 3 * S];
    float4 v = make_float4(a.x + b.x + cc.x + d.x, a.y + b.y + cc.y + d.y,
                           a.z + b.z + cc.z + d.z, a.w + b.w + cc.w + d.w);
    bool isW = (c < 512);
    int xc = isW ? c : (c - 512);
    float4 xv = *(const float4*)&xn[(size_t)n * D_DIM + xc];
    float4 yr;                                    // y (writes half) or resid (xhat half)
    if (isW) yr = make_float4(xv.x + v.x, xv.y + v.y, xv.z + v.z, xv.w + v.w);
    else     yr = make_float4(xv.x - v.x, xv.y - v.y, xv.z - v.z, xv.w - v.w);
    float local = yr.x*yr.x + yr.y*yr.y + yr.z*yr.z + yr.w*yr.w;

    __shared__ float red[256];
    __shared__ float sinv;
    red[t] = local;
    __syncthreads();
    for (int s = 64; s > 0; s >>= 1) {
        if ((t & 127) < s) red[t] += red[t + s];
        __syncthreads();
    }
    if (t == 0) {
        uncap[n] = red[128];                      // sum resid^2
        sinv = 1.0f / fmaxf(sqrtf(red[0]), EPSV); // from sum y^2
    }
    __syncthreads();
    if (isW) {
        float inv = sinv;
        *(float4*)&x_out[(size_t)n * D_DIM + c] =
            make_float4(yr.x*inv, yr.y*inv, yr.z*inv, yr.w*inv);
        ushort4v o;
        o[0] = f2b(yr.x); o[1] = f2b(yr.y); o[2] = f2b(yr.z); o[3] = f2b(yr.w);
        *(ushort4v*)&wb[(size_t)n * 512 + c] = o;
    }
}

// ---------------- final scalar reductions + counts ----------------
__global__ __launch_bounds__(256) void k_finalize(const float* __restrict__ uncap,
                                                  const float* __restrict__ writer_part,
                                                  const int* __restrict__ counts,
                                                  float* __restrict__ out)
{
    __shared__ float ru[256], rw[256];
    int t = threadIdx.x;
    float su = 0.f;
    for (int i = t; i < N_TOK; i += 256) su += uncap[i];
    float sw = writer_part[t];                    // exactly 256 partials
    ru[t] = su; rw[t] = sw;
    __syncthreads();
    for (int s = 128; s > 0; s >>= 1) {
        if (t < s) { ru[t] += ru[t + s]; rw[t] += rw[t + s]; }
        __syncthreads();
    }
    if (t == 0)
        out[(size_t)N_TOK * D_DIM] = ru[0] / (float)N_TOK
                                   + rw[0] / (float)(N_TOK * K_TOP * B_DIM);
    for (int i = t; i < M_EXP; i += 256)
        out[(size_t)N_TOK * D_DIM + 1 + i] = (float)counts[i];
}

extern "C" void kernel_launch(void* const* d_in, const int* in_sizes, int n_in,
                              void* d_out, int out_size, void* d_ws, size_t ws_size,
                              hipStream_t stream)
{
    const float* x = (const float*)d_in[0];
    const float* V = (const float*)d_in[1];
    const float* U = (const float*)d_in[2];
    float* out = (float*)d_out;

    float* ws     = (float*)d_ws;
    float* xn     = ws;                        // 2,097,152 f  (8.4 MB)
    float* P      = xn + 2097152;              // 16,777,216 f (67.1 MB): GEMM1 energy,
                                               //   then GEMM23 split-K partials
    float* uncap  = P + 16777216;              // 4096 f
    float* writer_part = uncap + 4096;         // 256 f (+pad)
    int*   topk_i = (int*)(writer_part + 512); // 65,536 i
    int*   counts = topk_i + 65536;            // 512 i (+pad)
    float* partV  = (float*)(counts + 1024);   // 65,536 f
    float* partU  = partV + 65536;             // 65,536 f
    unsigned short* hbf = (unsigned short*)(partU + 65536);  // 16,777,216 us (33.6 MB)
    unsigned short* U2t = hbf + 16777216;      // 2,097,152 us (4.2 MB)
    unsigned short* WXt = U2t + 2097152;       // 4,194,304 us (8.4 MB)
    unsigned short* R   = WXt + 4194304;       // 12,582,912 us (25.2 MB)
    unsigned short* Abf  = R;                  // 6,291,456 us (gemm1 A')
    unsigned short* Btbf = R + 6291456;        // 6,291,456 us (gemm1 B')
    unsigned short* writesb = R;               // 2,097,152 us (aliases Abf after GEMM1)
    float* energy = P;                         // 2,097,152 f ⊂ P
    // total ws use ~148 MB

    k_norm_x    <<<N_TOK / 4, 256, 0, stream>>>(x, xn, Abf, counts);
    k_uvnorm_part<<<512, 256, 0, stream>>>(V, U, partV, partU);
    k_norm_UV2  <<<512, 256, 0, stream>>>(V, U, partV, partU, Btbf, WXt, U2t);
    // GEMM1: h = A'(4096x1536) @ B'(1536x4096) -> hbf bf16 + energy fp32 (epilogue-fused)
    k_gemm8<KTOT, KTOT, 16, 1, 4096, 3><<<256, 512, 0, stream>>>(Abf, Btbf, energy, hbf);
    k_topk2     <<<N_TOK / 4, 256, 0, stream>>>(energy, hbf, topk_i, counts);
    // GEMM23: partial[ks] = hbf(4096x4096, K-slice ks) @ WXt^T -> 4x(4096x1024) in P
    k_gemm8<4096, 1024, 4, 4, 1024, 0><<<256, 512, 0, stream>>>(hbf, WXt, P, nullptr);
    // fused reduce + x_out + uncap + writes bf16
    k_reduce_fin<<<4096, 256, 0, stream>>>(P, xn, out, writesb, uncap);
    // GEMM4 fused writer-loss: hrecon tile vs hbf, per-block partials (no hrecon write)
    k_gemm8<D_DIM, D_DIM, 16, 1, 4096, 4><<<256, 512, 0, stream>>>(writesb, U2t, writer_part, hbf);
    k_finalize  <<<1, 256, 0, stream>>>(uncap, writer_part, counts, out);
}